// Round 2
// baseline (2007.491 us; speedup 1.0000x reference)
//
#include <hip/hip_runtime.h>
#include <stdint.h>

// ---------------------------------------------------------------------------
// PairwiseAttentionLinear — fp32 in/out on device (reference is jnp.float32).
// Strategy: device-side fp32->bf16 cast of weights/activations, bf16 MFMA
// GEMMs (16x16x32) with fp32 accumulation, fp32 residual stream when ws fits.
// GEMM: 128x128 tile, BK=32, 4 waves, reg-staged LDS (de-risked; no
// global_load_lds this round).
// ---------------------------------------------------------------------------

typedef __bf16 bf16x8 __attribute__((ext_vector_type(8)));
typedef float f32x4 __attribute__((ext_vector_type(4)));

static __device__ __forceinline__ float bf2f(unsigned short u) {
  unsigned int x = ((unsigned int)u) << 16;
  float f;
  __builtin_memcpy(&f, &x, 4);
  return f;
}
static __device__ __forceinline__ unsigned short f2bf(float f) {
  unsigned int x;
  __builtin_memcpy(&x, &f, 4);
  x += 0x7fffu + ((x >> 16) & 1u);  // RNE
  return (unsigned short)(x >> 16);
}

// fp32 -> bf16, 4 elems/thread; n always a multiple of 1024 here.
__global__ __launch_bounds__(256) void cvt_kernel(
    const float* __restrict__ in, unsigned short* __restrict__ out, long n) {
  const long i = ((long)blockIdx.x * 256 + threadIdx.x) * 4;
  if (i + 3 < n) {
    float4 f = *(const float4*)(in + i);
    *(ushort4*)(out + i) = make_ushort4(f2bf(f.x), f2bf(f.y), f2bf(f.z), f2bf(f.w));
  }
}

// ---------------------------------------------------------------------------
// GEMM: C[i,j] = act( sum_k A[i,k]*B[j,k] + bias[j] ) [+ res[i,j]]
// A bf16 (lda), B bf16 NxK row-major (= W, since ref does x @ W.T).
// bias fp32 or null. res_mode: 0 none, 1 fp32, 2 bf16. out_f32: 0 bf16, 1 f32.
// grid = (N/128, 8192/128), block = 256 (4 waves, 2x2 of 64x64).
// ---------------------------------------------------------------------------
__global__ __launch_bounds__(256) void gemm_bt_kernel(
    const unsigned short* __restrict__ A, int lda,
    const unsigned short* __restrict__ B, int K,
    void* __restrict__ Cp, int ldc,
    const float* __restrict__ bias,
    const void* __restrict__ res, int res_mode, int ldres,
    int relu, int out_f32) {
  __shared__ __align__(16) unsigned short As[128 * 32];
  __shared__ __align__(16) unsigned short Bs[128 * 32];

  const int t = threadIdx.x;
  const int lane = t & 63;
  const int w = t >> 6;
  const int wr = (w >> 1) * 64;
  const int wc = (w & 1) * 64;
  const long brow = (long)blockIdx.y * 128;
  const long bcol = (long)blockIdx.x * 128;

  // staging: wave w owns tile rows [w*32, w*32+32); lane l -> row l/4 (+0/+16),
  // col (l%4)*8.
  const int srow = lane >> 2;
  const int scol = (lane & 3) * 8;
  const unsigned short* Ab = A + (brow + w * 32 + srow) * (long)lda + scol;
  const unsigned short* Bb = B + (bcol + w * 32 + srow) * (long)K + scol;
  unsigned short* As0 = &As[(w * 32 + srow) * 32 + scol];
  unsigned short* Bs0 = &Bs[(w * 32 + srow) * 32 + scol];

  f32x4 acc[4][4];
  const f32x4 fzero = {0.f, 0.f, 0.f, 0.f};
#pragma unroll
  for (int m = 0; m < 4; ++m)
#pragma unroll
    for (int n = 0; n < 4; ++n) acc[m][n] = fzero;

  const int fr = lane & 15;        // row (A) / col (B) within fragment
  const int fk = (lane >> 4) * 8;  // k-offset

  for (int kt = 0; kt < K; kt += 32) {
    bf16x8 a0 = *(const bf16x8*)(Ab + kt);
    bf16x8 a1 = *(const bf16x8*)(Ab + 16 * (long)lda + kt);
    bf16x8 b0 = *(const bf16x8*)(Bb + kt);
    bf16x8 b1 = *(const bf16x8*)(Bb + 16 * (long)K + kt);
    __syncthreads();  // previous iter's LDS reads complete
    *(bf16x8*)As0 = a0;
    *(bf16x8*)(As0 + 16 * 32) = a1;
    *(bf16x8*)Bs0 = b0;
    *(bf16x8*)(Bs0 + 16 * 32) = b1;
    __syncthreads();

    bf16x8 af[4], bfv[4];
#pragma unroll
    for (int m = 0; m < 4; ++m)
      af[m] = *(const bf16x8*)&As[(wr + m * 16 + fr) * 32 + fk];
#pragma unroll
    for (int n = 0; n < 4; ++n)
      bfv[n] = *(const bf16x8*)&Bs[(wc + n * 16 + fr) * 32 + fk];
#pragma unroll
    for (int m = 0; m < 4; ++m)
#pragma unroll
      for (int n = 0; n < 4; ++n)
        acc[m][n] = __builtin_amdgcn_mfma_f32_16x16x32_bf16(af[m], bfv[n],
                                                            acc[m][n], 0, 0, 0);
  }

  // C/D layout: col = lane&15, row = (lane>>4)*4 + reg  [m89-verified]
  const long rbase = brow + wr + (lane >> 4) * 4;
#pragma unroll
  for (int m = 0; m < 4; ++m) {
#pragma unroll
    for (int n = 0; n < 4; ++n) {
      const long col = bcol + wc + n * 16 + fr;
      const float bv = bias ? bias[col] : 0.f;
#pragma unroll
      for (int j = 0; j < 4; ++j) {
        const long r = rbase + m * 16 + j;
        float v = acc[m][n][j] + bv;
        if (relu) v = fmaxf(v, 0.f);
        if (res_mode == 1)
          v += ((const float*)res)[r * (long)ldres + col];
        else if (res_mode == 2)
          v += bf2f(((const unsigned short*)res)[r * (long)ldres + col]);
        if (out_f32)
          ((float*)Cp)[r * (long)ldc + col] = v;
        else
          ((unsigned short*)Cp)[r * (long)ldc + col] = f2bf(v);
      }
    }
  }
}

// ---------------------------------------------------------------------------
// LayerNorm over rows of length L; in fp32 or bf16; gains/biases fp32; out bf16.
// ---------------------------------------------------------------------------
template <int L>
__global__ __launch_bounds__(256) void ln_kernel(
    const void* __restrict__ inp, int in_bf16, int ldin,
    const float* __restrict__ g, const float* __restrict__ b,
    unsigned short* __restrict__ outp, int ldout) {
  constexpr int VEC = L / 256;
  const long row = blockIdx.x;
  const int t = threadIdx.x;
  float v[VEC];
  if (in_bf16) {
    const unsigned short* p = (const unsigned short*)inp + row * (long)ldin + t * VEC;
#pragma unroll
    for (int i = 0; i < VEC; i += 4) {
      ushort4 u = *(const ushort4*)(p + i);
      v[i] = bf2f(u.x); v[i + 1] = bf2f(u.y); v[i + 2] = bf2f(u.z); v[i + 3] = bf2f(u.w);
    }
  } else {
    const float* p = (const float*)inp + row * (long)ldin + t * VEC;
#pragma unroll
    for (int i = 0; i < VEC; i += 4) {
      float4 f = *(const float4*)(p + i);
      v[i] = f.x; v[i + 1] = f.y; v[i + 2] = f.z; v[i + 3] = f.w;
    }
  }
  float s = 0.f, sq = 0.f;
#pragma unroll
  for (int i = 0; i < VEC; ++i) { s += v[i]; sq += v[i] * v[i]; }
#pragma unroll
  for (int off = 32; off; off >>= 1) {
    s += __shfl_xor(s, off, 64);
    sq += __shfl_xor(sq, off, 64);
  }
  __shared__ float red[8];
  if ((t & 63) == 0) { red[t >> 6] = s; red[4 + (t >> 6)] = sq; }
  __syncthreads();
  s = red[0] + red[1] + red[2] + red[3];
  sq = red[4] + red[5] + red[6] + red[7];
  const float mean = s * (1.f / L);
  const float var = sq * (1.f / L) - mean * mean;
  const float rstd = rsqrtf(var + 1e-6f);
  unsigned short* op = outp + row * (long)ldout + t * VEC;
  const float* gp = g + t * VEC;
  const float* bp = b + t * VEC;
#pragma unroll
  for (int i = 0; i < VEC; i += 4) {
    float4 gg = *(const float4*)(gp + i);
    float4 bb = *(const float4*)(bp + i);
    *(ushort4*)(op + i) = make_ushort4(
        f2bf((v[i + 0] - mean) * rstd * gg.x + bb.x),
        f2bf((v[i + 1] - mean) * rstd * gg.y + bb.y),
        f2bf((v[i + 2] - mean) * rstd * gg.z + bb.z),
        f2bf((v[i + 3] - mean) * rstd * gg.w + bb.w));
  }
}

// ---------------------------------------------------------------------------
// Pairwise attention glue. Q/K/V bf16 [8192,2048]; per head (8) p in {0,1},
// DK=128. s = q.k * 1/sqrt(128); 2-wide softmax; o = a@v; out = o + res.
// res fp32 or bf16 (res_bf16); out fp32 or bf16 (out_bf16).
// Block 512 = 8 waves = 8 heads; lane owns dims {2*lane, 2*lane+1}.
// ---------------------------------------------------------------------------
__global__ __launch_bounds__(512) void attn_glue_kernel(
    const unsigned short* __restrict__ Q, const unsigned short* __restrict__ Kq,
    const unsigned short* __restrict__ V, const void* __restrict__ Xres,
    int res_bf16, void* __restrict__ Xout, int out_bf16) {
  const long row = blockIdx.x;
  const int h = threadIdx.x >> 6;
  const int lane = threadIdx.x & 63;
  const long base = row * 2048 + h * 256;
  const int d = lane * 2;

  ushort2 q0 = *(const ushort2*)&Q[base + d];
  ushort2 q1 = *(const ushort2*)&Q[base + 128 + d];
  ushort2 k0 = *(const ushort2*)&Kq[base + d];
  ushort2 k1 = *(const ushort2*)&Kq[base + 128 + d];
  ushort2 v0 = *(const ushort2*)&V[base + d];
  ushort2 v1 = *(const ushort2*)&V[base + 128 + d];

  const float q0x = bf2f(q0.x), q0y = bf2f(q0.y);
  const float q1x = bf2f(q1.x), q1y = bf2f(q1.y);
  const float k0x = bf2f(k0.x), k0y = bf2f(k0.y);
  const float k1x = bf2f(k1.x), k1y = bf2f(k1.y);

  float s00 = q0x * k0x + q0y * k0y;
  float s01 = q0x * k1x + q0y * k1y;
  float s10 = q1x * k0x + q1y * k0y;
  float s11 = q1x * k1x + q1y * k1y;
#pragma unroll
  for (int off = 32; off; off >>= 1) {
    s00 += __shfl_xor(s00, off, 64);
    s01 += __shfl_xor(s01, off, 64);
    s10 += __shfl_xor(s10, off, 64);
    s11 += __shfl_xor(s11, off, 64);
  }
  const float SC = 0.088388347648318447f;  // 1/sqrt(128)
  s00 *= SC; s01 *= SC; s10 *= SC; s11 *= SC;
  const float m0 = fmaxf(s00, s01), m1 = fmaxf(s10, s11);
  const float e00 = __expf(s00 - m0), e01 = __expf(s01 - m0);
  const float e10 = __expf(s10 - m1), e11 = __expf(s11 - m1);
  const float i0 = 1.f / (e00 + e01), i1 = 1.f / (e10 + e11);
  const float a00 = e00 * i0, a01 = e01 * i0;
  const float a10 = e10 * i1, a11 = e11 * i1;

  const float v0x = bf2f(v0.x), v0y = bf2f(v0.y);
  const float v1x = bf2f(v1.x), v1y = bf2f(v1.y);
  float o0x = a00 * v0x + a01 * v1x, o0y = a00 * v0y + a01 * v1y;
  float o1x = a10 * v0x + a11 * v1x, o1y = a10 * v0y + a11 * v1y;

  if (res_bf16) {
    const unsigned short* xr = (const unsigned short*)Xres + base;
    ushort2 ra = *(const ushort2*)&xr[d];
    ushort2 rb = *(const ushort2*)&xr[128 + d];
    o0x += bf2f(ra.x); o0y += bf2f(ra.y); o1x += bf2f(rb.x); o1y += bf2f(rb.y);
  } else {
    const float* xr = (const float*)Xres + base;
    float2 ra = *(const float2*)&xr[d];
    float2 rb = *(const float2*)&xr[128 + d];
    o0x += ra.x; o0y += ra.y; o1x += rb.x; o1y += rb.y;
  }
  if (out_bf16) {
    unsigned short* xo = (unsigned short*)Xout + base;
    *(ushort2*)&xo[d] = make_ushort2(f2bf(o0x), f2bf(o0y));
    *(ushort2*)&xo[128 + d] = make_ushort2(f2bf(o1x), f2bf(o1y));
  } else {
    float* xo = (float*)Xout + base;
    *(float2*)&xo[d] = make_float2(o0x, o0y);
    *(float2*)&xo[128 + d] = make_float2(o1x, o1y);
  }
}

// out[row] = dot(H[row,0:1024] (bf16), w (f32)) + b ; fp32 out.
__global__ __launch_bounds__(256) void final_matvec_kernel(
    const unsigned short* __restrict__ Hm, const float* __restrict__ wv,
    const float* __restrict__ b2, float* __restrict__ outp) {
  const long row = blockIdx.x;
  const int t = threadIdx.x;
  ushort4 hv = *(const ushort4*)&Hm[row * 1024 + t * 4];
  float4 wq = *(const float4*)&wv[t * 4];
  float s = bf2f(hv.x) * wq.x + bf2f(hv.y) * wq.y +
            bf2f(hv.z) * wq.z + bf2f(hv.w) * wq.w;
#pragma unroll
  for (int off = 32; off; off >>= 1) s += __shfl_xor(s, off, 64);
  __shared__ float red[4];
  if ((t & 63) == 0) red[t >> 6] = s;
  __syncthreads();
  if (t == 0) outp[row] = red[0] + red[1] + red[2] + red[3] + b2[0];
}

// ---------------------------------------------------------------------------
extern "C" void kernel_launch(void* const* d_in, const int* in_sizes, int n_in,
                              void* d_out, int out_size, void* d_ws,
                              size_t ws_size, hipStream_t stream) {
  const float* x_in = (const float*)d_in[0];
  const float* aln_g = (const float*)d_in[1];
  const float* aln_b = (const float*)d_in[2];
  const float* Wq_f = (const float*)d_in[3];
  const float* Wk_f = (const float*)d_in[4];
  const float* Wv_f = (const float*)d_in[5];
  const float* lnd_g = (const float*)d_in[6];
  const float* lnd_b = (const float*)d_in[7];
  const float* lnt_g = (const float*)d_in[8];
  const float* lnt_b = (const float*)d_in[9];
  const float* Wd1_f = (const float*)d_in[10];
  const float* bd1 = (const float*)d_in[11];
  const float* Wd2_f = (const float*)d_in[12];
  const float* bd2 = (const float*)d_in[13];
  const float* Wt1_f = (const float*)d_in[14];
  const float* bt1 = (const float*)d_in[15];
  const float* Wt2_f = (const float*)d_in[16];
  const float* bt2 = (const float*)d_in[17];
  const float* Wo1_f = (const float*)d_in[18];
  const float* bo1 = (const float*)d_in[19];
  const float* Wo2_f = (const float*)d_in[20];
  const float* bo2 = (const float*)d_in[21];

  const size_t R = 8192, D = 2048, HD = 1024;
  const size_t PLB = R * D * 2;               // bf16 plane: 32 MiB
  const size_t XF = R * D * 4;                // fp32 X: 64 MiB
  const size_t WALL = (3 * 3 * D * D + 4 * 2 * D * HD + HD * D) * 2;  // 108 MiB
  const size_t SLOT = D * D * 2;              // 8 MiB
  const bool planAll = ws_size >= XF + 4 * PLB + WALL;   // ~300 MiB
  const bool xIsF32 = planAll || ws_size >= XF + 4 * PLB + SLOT;  // ~200 MiB

  char* p = (char*)d_ws;
  float* Xf = nullptr;
  unsigned short* Xb = nullptr;
  if (xIsF32) { Xf = (float*)p; p += XF; } else { Xb = (unsigned short*)p; p += PLB; }
  unsigned short* XN = (unsigned short*)p; p += PLB;
  unsigned short* Qb = (unsigned short*)p; p += PLB;
  unsigned short* Kb = (unsigned short*)p; p += PLB;
  unsigned short* Vb = (unsigned short*)p; p += PLB;
  unsigned short* Warea = (unsigned short*)p;  // WALL (planAll) or SLOT

  void* X = xIsF32 ? (void*)Xf : (void*)Xb;
  const int xres_mode = xIsF32 ? 1 : 2;  // gemm res_mode for X
  unsigned short* H1 = Qb;
  unsigned short* DN = XN;
  unsigned short* TN = XN + R * HD;
  unsigned short* Hfin = Vb;

  auto cvt = [&](const float* src, unsigned short* dst, long n) {
    cvt_kernel<<<dim3((unsigned)(n / 1024)), dim3(256), 0, stream>>>(src, dst, n);
  };

  // Pre-converted weight pointers (planAll) -----------------------------------
  unsigned short* Wq_b = Warea;
  unsigned short* Wk_b = Wq_b + 3 * D * D;
  unsigned short* Wv_b = Wk_b + 3 * D * D;
  unsigned short* Wd1_b = Wv_b + 3 * D * D;
  unsigned short* Wd2_b = Wd1_b + 2 * D * HD;
  unsigned short* Wt1_b = Wd2_b + 2 * D * HD;
  unsigned short* Wt2_b = Wt1_b + 2 * D * HD;
  unsigned short* Wo1_b = Wt2_b + 2 * D * HD;
  if (planAll) {
    cvt(Wq_f, Wq_b, 3 * D * D);
    cvt(Wk_f, Wk_b, 3 * D * D);
    cvt(Wv_f, Wv_b, 3 * D * D);
    cvt(Wd1_f, Wd1_b, 2 * D * HD);
    cvt(Wd2_f, Wd2_b, 2 * D * HD);
    cvt(Wt1_f, Wt1_b, 2 * D * HD);
    cvt(Wt2_f, Wt2_b, 2 * D * HD);
    cvt(Wo1_f, Wo1_b, HD * D);
  }
  // Returns bf16 weight pointer; converts into slot if not pre-converted.
  auto wbf = [&](const float* src_base, unsigned short* pre_base, size_t off,
                 size_t cnt) -> const unsigned short* {
    if (planAll) return pre_base + off;
    cvt(src_base + off, Warea, (long)cnt);
    return Warea;
  };

  auto gemm = [&](const unsigned short* A, int lda, const unsigned short* B,
                  int N, int K, void* C, int ldc, const float* bias,
                  const void* res, int res_mode, int ldres, int relu, int of32) {
    dim3 grid(N / 128, 8192 / 128);
    gemm_bt_kernel<<<grid, dim3(256), 0, stream>>>(
        A, lda, B, K, C, ldc, bias, res, res_mode, ldres, relu, of32);
  };

  for (int n = 0; n < 3; ++n) {
    const void* lin = (n == 0) ? (const void*)x_in : (const void*)X;
    const int lin_bf16 = (n == 0) ? 0 : (xIsF32 ? 0 : 1);
    ln_kernel<2048><<<8192, 256, 0, stream>>>(lin, lin_bf16, 2048,
                                              aln_g + n * D, aln_b + n * D, XN, 2048);
    const size_t wo = (size_t)n * D * D;
    gemm(XN, 2048, wbf(Wq_f, Wq_b, wo, D * D), 2048, 2048, Qb, 2048,
         nullptr, nullptr, 0, 0, 0, 0);
    gemm(XN, 2048, wbf(Wk_f, Wk_b, wo, D * D), 2048, 2048, Kb, 2048,
         nullptr, nullptr, 0, 0, 0, 0);
    gemm(XN, 2048, wbf(Wv_f, Wv_b, wo, D * D), 2048, 2048, Vb, 2048,
         nullptr, nullptr, 0, 0, 0, 0);
    attn_glue_kernel<<<8192, 512, 0, stream>>>(
        Qb, Kb, Vb, (n == 0) ? (const void*)x_in : (const void*)X,
        (n == 0) ? 0 : (xIsF32 ? 0 : 1), X, xIsF32 ? 0 : 1);

    if (n < 2) {
      const size_t fo = (size_t)n * D * HD;
      ln_kernel<1024><<<8192, 256, 0, stream>>>(X, !xIsF32, 2048,
                                                lnd_g + n * HD, lnd_b + n * HD, DN, 1024);
      const void* Xt = xIsF32 ? (const void*)(Xf + HD) : (const void*)(Xb + HD);
      ln_kernel<1024><<<8192, 256, 0, stream>>>(Xt, !xIsF32, 2048,
                                                lnt_g + n * HD, lnt_b + n * HD, TN, 1024);
      void* Xd2 = X;
      void* Xt2 = xIsF32 ? (void*)(Xf + HD) : (void*)(Xb + HD);
      // d path: H1 = relu(DN @ Wd1^T + bd1); X[:, :1024] = H1 @ Wd2^T + bd2 + X
      gemm(DN, 1024, wbf(Wd1_f, Wd1_b, fo, D * HD), 2048, 1024, H1, 2048,
           bd1 + n * D, nullptr, 0, 0, 1, 0);
      gemm(H1, 2048, wbf(Wd2_f, Wd2_b, fo, D * HD), 1024, 2048, Xd2, 2048,
           bd2 + n * HD, Xd2, xres_mode, 2048, 0, xIsF32 ? 1 : 0);
      // t path
      gemm(TN, 1024, wbf(Wt1_f, Wt1_b, fo, D * HD), 2048, 1024, H1, 2048,
           bt1 + n * D, nullptr, 0, 0, 1, 0);
      gemm(H1, 2048, wbf(Wt2_f, Wt2_b, fo, D * HD), 1024, 2048, Xt2, 2048,
           bt2 + n * HD, Xt2, xres_mode, 2048, 0, xIsF32 ? 1 : 0);
    }
  }

  // final head: Hfin = relu(x @ Wo1^T + bo1); out = Hfin @ Wo2^T + bo2
  const unsigned short* Afin;
  if (xIsF32) {
    cvt((const float*)Xf, XN, (long)(R * D));
    Afin = XN;
  } else {
    Afin = Xb;
  }
  gemm(Afin, 2048, wbf(Wo1_f, Wo1_b, 0, HD * D), 1024, 2048, Hfin, 1024,
       bo1, nullptr, 0, 0, 1, 0);
  final_matvec_kernel<<<8192, 256, 0, stream>>>(Hfin, Wo2_f, bo2, (float*)d_out);
}

// Round 3
// 1983.388 us; speedup vs baseline: 1.0122x; 1.0122x over previous
//
#include <hip/hip_runtime.h>
#include <stdint.h>

// ---------------------------------------------------------------------------
// PairwiseAttentionLinear — fp32 in/out on device.
// Device-side fp32->bf16 weight cast, bf16 MFMA GEMMs (16x16x32) w/ fp32 acc,
// fp32 residual stream. GEMM: m97 structure — 128x128 tile, BK=32, 4 waves,
// global_load_lds width=16 staging (this round's single change vs round 2),
// 2 barriers per K-step.
// ---------------------------------------------------------------------------

typedef __bf16 bf16x8 __attribute__((ext_vector_type(8)));
typedef float f32x4 __attribute__((ext_vector_type(4)));

static __device__ __forceinline__ float bf2f(unsigned short u) {
  unsigned int x = ((unsigned int)u) << 16;
  float f;
  __builtin_memcpy(&f, &x, 4);
  return f;
}
static __device__ __forceinline__ unsigned short f2bf(float f) {
  unsigned int x;
  __builtin_memcpy(&x, &f, 4);
  x += 0x7fffu + ((x >> 16) & 1u);  // RNE
  return (unsigned short)(x >> 16);
}

// global -> LDS direct copy, 16 B/lane. LDS dest is wave-uniform base;
// HW writes lane l at base + l*16 [m104/m108]. Generic->AS casts are
// addrspacecasts handled by the backend.
static __device__ __forceinline__ void gload_lds16(const void* g, void* l) {
  __builtin_amdgcn_global_load_lds(
      (const __attribute__((address_space(1))) unsigned int*)g,
      (__attribute__((address_space(3))) unsigned int*)l, 16, 0, 0);
}

// fp32 -> bf16, 4 elems/thread; n a multiple of 1024.
__global__ __launch_bounds__(256) void cvt_kernel(
    const float* __restrict__ in, unsigned short* __restrict__ out, long n) {
  const long i = ((long)blockIdx.x * 256 + threadIdx.x) * 4;
  if (i + 3 < n) {
    float4 f = *(const float4*)(in + i);
    *(ushort4*)(out + i) = make_ushort4(f2bf(f.x), f2bf(f.y), f2bf(f.z), f2bf(f.w));
  }
}

// ---------------------------------------------------------------------------
// GEMM: C[i,j] = act( sum_k A[i,k]*B[j,k] + bias[j] ) [+ res[i,j]]
// A bf16 (lda), B bf16 NxK row-major. res_mode: 0 none, 1 fp32, 2 bf16.
// grid = (N/128, M/128), block = 256 (4 waves, 2x2 of 64x64).
// ---------------------------------------------------------------------------
__global__ __launch_bounds__(256) void gemm_bt_kernel(
    const unsigned short* __restrict__ A, int lda,
    const unsigned short* __restrict__ B, int K,
    void* __restrict__ Cp, int ldc,
    const float* __restrict__ bias,
    const void* __restrict__ res, int res_mode, int ldres,
    int relu, int out_f32) {
  __shared__ __align__(16) unsigned short As[128 * 32];
  __shared__ __align__(16) unsigned short Bs[128 * 32];

  const int t = threadIdx.x;
  const int lane = t & 63;
  const int w = t >> 6;
  const int wr = (w >> 1) * 64;
  const int wc = (w & 1) * 64;
  const long brow = (long)blockIdx.y * 128;
  const long bcol = (long)blockIdx.x * 128;

  // staging: wave w owns tile rows [w*32, w*32+32) in two 16-row chunks;
  // lane l -> row l/4, col (l%4)*8  (offset l*16 B == linear LDS dest).
  const int srow = lane >> 2;
  const int scol = (lane & 3) * 8;
  const unsigned short* Ab = A + (brow + w * 32 + srow) * (long)lda + scol;
  const unsigned short* Bb = B + (bcol + w * 32 + srow) * (long)K + scol;
  unsigned short* Asb = &As[(w * 32) * 32];
  unsigned short* Bsb = &Bs[(w * 32) * 32];

  f32x4 acc[4][4];
  const f32x4 fzero = {0.f, 0.f, 0.f, 0.f};
#pragma unroll
  for (int m = 0; m < 4; ++m)
#pragma unroll
    for (int n = 0; n < 4; ++n) acc[m][n] = fzero;

  const int fr = lane & 15;        // row (A) / col (B) within fragment
  const int fk = (lane >> 4) * 8;  // k-offset

  for (int kt = 0; kt < K; kt += 32) {
    gload_lds16(Ab + kt, Asb);
    gload_lds16(Ab + 16 * (long)lda + kt, Asb + 16 * 32);
    gload_lds16(Bb + kt, Bsb);
    gload_lds16(Bb + 16 * (long)K + kt, Bsb + 16 * 32);
    __syncthreads();  // compiler drains vmcnt(0) before s_barrier

    bf16x8 af[4], bfv[4];
#pragma unroll
    for (int m = 0; m < 4; ++m)
      af[m] = *(const bf16x8*)&As[(wr + m * 16 + fr) * 32 + fk];
#pragma unroll
    for (int n = 0; n < 4; ++n)
      bfv[n] = *(const bf16x8*)&Bs[(wc + n * 16 + fr) * 32 + fk];
#pragma unroll
    for (int m = 0; m < 4; ++m)
#pragma unroll
      for (int n = 0; n < 4; ++n)
        acc[m][n] = __builtin_amdgcn_mfma_f32_16x16x32_bf16(af[m], bfv[n],
                                                            acc[m][n], 0, 0, 0);
    __syncthreads();  // LDS reads complete before next stage overwrites
  }

  // C/D layout: col = lane&15, row = (lane>>4)*4 + reg  [m89-verified]
  const long rbase = brow + wr + (lane >> 4) * 4;
#pragma unroll
  for (int m = 0; m < 4; ++m) {
#pragma unroll
    for (int n = 0; n < 4; ++n) {
      const long col = bcol + wc + n * 16 + fr;
      const float bv = bias ? bias[col] : 0.f;
#pragma unroll
      for (int j = 0; j < 4; ++j) {
        const long r = rbase + m * 16 + j;
        float v = acc[m][n][j] + bv;
        if (relu) v = fmaxf(v, 0.f);
        if (res_mode == 1)
          v += ((const float*)res)[r * (long)ldres + col];
        else if (res_mode == 2)
          v += bf2f(((const unsigned short*)res)[r * (long)ldres + col]);
        if (out_f32)
          ((float*)Cp)[r * (long)ldc + col] = v;
        else
          ((unsigned short*)Cp)[r * (long)ldc + col] = f2bf(v);
      }
    }
  }
}

// ---------------------------------------------------------------------------
// LayerNorm over rows of length L; in fp32 or bf16; g/b fp32; out bf16.
// ---------------------------------------------------------------------------
template <int L>
__global__ __launch_bounds__(256) void ln_kernel(
    const void* __restrict__ inp, int in_bf16, int ldin,
    const float* __restrict__ g, const float* __restrict__ b,
    unsigned short* __restrict__ outp, int ldout) {
  constexpr int VEC = L / 256;
  const long row = blockIdx.x;
  const int t = threadIdx.x;
  float v[VEC];
  if (in_bf16) {
    const unsigned short* p = (const unsigned short*)inp + row * (long)ldin + t * VEC;
#pragma unroll
    for (int i = 0; i < VEC; i += 4) {
      ushort4 u = *(const ushort4*)(p + i);
      v[i] = bf2f(u.x); v[i + 1] = bf2f(u.y); v[i + 2] = bf2f(u.z); v[i + 3] = bf2f(u.w);
    }
  } else {
    const float* p = (const float*)inp + row * (long)ldin + t * VEC;
#pragma unroll
    for (int i = 0; i < VEC; i += 4) {
      float4 f = *(const float4*)(p + i);
      v[i] = f.x; v[i + 1] = f.y; v[i + 2] = f.z; v[i + 3] = f.w;
    }
  }
  float s = 0.f, sq = 0.f;
#pragma unroll
  for (int i = 0; i < VEC; ++i) { s += v[i]; sq += v[i] * v[i]; }
#pragma unroll
  for (int off = 32; off; off >>= 1) {
    s += __shfl_xor(s, off, 64);
    sq += __shfl_xor(sq, off, 64);
  }
  __shared__ float red[8];
  if ((t & 63) == 0) { red[t >> 6] = s; red[4 + (t >> 6)] = sq; }
  __syncthreads();
  s = red[0] + red[1] + red[2] + red[3];
  sq = red[4] + red[5] + red[6] + red[7];
  const float mean = s * (1.f / L);
  const float var = sq * (1.f / L) - mean * mean;
  const float rstd = rsqrtf(var + 1e-6f);
  unsigned short* op = outp + row * (long)ldout + t * VEC;
  const float* gp = g + t * VEC;
  const float* bp = b + t * VEC;
#pragma unroll
  for (int i = 0; i < VEC; i += 4) {
    float4 gg = *(const float4*)(gp + i);
    float4 bb = *(const float4*)(bp + i);
    *(ushort4*)(op + i) = make_ushort4(
        f2bf((v[i + 0] - mean) * rstd * gg.x + bb.x),
        f2bf((v[i + 1] - mean) * rstd * gg.y + bb.y),
        f2bf((v[i + 2] - mean) * rstd * gg.z + bb.z),
        f2bf((v[i + 3] - mean) * rstd * gg.w + bb.w));
  }
}

// ---------------------------------------------------------------------------
// Pairwise attention glue. Q/K/V bf16 [8192,2048]; 8 heads, 2 positions,
// DK=128. Optional extra bf16 copy of the fp32 output (Xout_bf).
// Block 512 = 8 waves = 8 heads; lane owns dims {2*lane, 2*lane+1}.
// ---------------------------------------------------------------------------
__global__ __launch_bounds__(512) void attn_glue_kernel(
    const unsigned short* __restrict__ Q, const unsigned short* __restrict__ Kq,
    const unsigned short* __restrict__ V, const void* __restrict__ Xres,
    int res_bf16, void* __restrict__ Xout, int out_bf16,
    unsigned short* __restrict__ Xout_bf) {
  const long row = blockIdx.x;
  const int h = threadIdx.x >> 6;
  const int lane = threadIdx.x & 63;
  const long base = row * 2048 + h * 256;
  const int d = lane * 2;

  ushort2 q0 = *(const ushort2*)&Q[base + d];
  ushort2 q1 = *(const ushort2*)&Q[base + 128 + d];
  ushort2 k0 = *(const ushort2*)&Kq[base + d];
  ushort2 k1 = *(const ushort2*)&Kq[base + 128 + d];
  ushort2 v0 = *(const ushort2*)&V[base + d];
  ushort2 v1 = *(const ushort2*)&V[base + 128 + d];

  const float q0x = bf2f(q0.x), q0y = bf2f(q0.y);
  const float q1x = bf2f(q1.x), q1y = bf2f(q1.y);
  const float k0x = bf2f(k0.x), k0y = bf2f(k0.y);
  const float k1x = bf2f(k1.x), k1y = bf2f(k1.y);

  float s00 = q0x * k0x + q0y * k0y;
  float s01 = q0x * k1x + q0y * k1y;
  float s10 = q1x * k0x + q1y * k0y;
  float s11 = q1x * k1x + q1y * k1y;
#pragma unroll
  for (int off = 32; off; off >>= 1) {
    s00 += __shfl_xor(s00, off, 64);
    s01 += __shfl_xor(s01, off, 64);
    s10 += __shfl_xor(s10, off, 64);
    s11 += __shfl_xor(s11, off, 64);
  }
  const float SC = 0.088388347648318447f;  // 1/sqrt(128)
  s00 *= SC; s01 *= SC; s10 *= SC; s11 *= SC;
  const float m0 = fmaxf(s00, s01), m1 = fmaxf(s10, s11);
  const float e00 = __expf(s00 - m0), e01 = __expf(s01 - m0);
  const float e10 = __expf(s10 - m1), e11 = __expf(s11 - m1);
  const float i0 = 1.f / (e00 + e01), i1 = 1.f / (e10 + e11);
  const float a00 = e00 * i0, a01 = e01 * i0;
  const float a10 = e10 * i1, a11 = e11 * i1;

  const float v0x = bf2f(v0.x), v0y = bf2f(v0.y);
  const float v1x = bf2f(v1.x), v1y = bf2f(v1.y);
  float o0x = a00 * v0x + a01 * v1x, o0y = a00 * v0y + a01 * v1y;
  float o1x = a10 * v0x + a11 * v1x, o1y = a10 * v0y + a11 * v1y;

  if (res_bf16) {
    const unsigned short* xr = (const unsigned short*)Xres + base;
    ushort2 ra = *(const ushort2*)&xr[d];
    ushort2 rb = *(const ushort2*)&xr[128 + d];
    o0x += bf2f(ra.x); o0y += bf2f(ra.y); o1x += bf2f(rb.x); o1y += bf2f(rb.y);
  } else {
    const float* xr = (const float*)Xres + base;
    float2 ra = *(const float2*)&xr[d];
    float2 rb = *(const float2*)&xr[128 + d];
    o0x += ra.x; o0y += ra.y; o1x += rb.x; o1y += rb.y;
  }
  if (out_bf16) {
    unsigned short* xo = (unsigned short*)Xout + base;
    *(ushort2*)&xo[d] = make_ushort2(f2bf(o0x), f2bf(o0y));
    *(ushort2*)&xo[128 + d] = make_ushort2(f2bf(o1x), f2bf(o1y));
  } else {
    float* xo = (float*)Xout + base;
    *(float2*)&xo[d] = make_float2(o0x, o0y);
    *(float2*)&xo[128 + d] = make_float2(o1x, o1y);
  }
  if (Xout_bf) {
    unsigned short* xb = Xout_bf + base;
    *(ushort2*)&xb[d] = make_ushort2(f2bf(o0x), f2bf(o0y));
    *(ushort2*)&xb[128 + d] = make_ushort2(f2bf(o1x), f2bf(o1y));
  }
}

// out[row] = dot(H[row,0:1024] (bf16), w (f32)) + b ; fp32 out.
__global__ __launch_bounds__(256) void final_matvec_kernel(
    const unsigned short* __restrict__ Hm, const float* __restrict__ wv,
    const float* __restrict__ b2, float* __restrict__ outp) {
  const long row = blockIdx.x;
  const int t = threadIdx.x;
  ushort4 hv = *(const ushort4*)&Hm[row * 1024 + t * 4];
  float4 wq = *(const float4*)&wv[t * 4];
  float s = bf2f(hv.x) * wq.x + bf2f(hv.y) * wq.y +
            bf2f(hv.z) * wq.z + bf2f(hv.w) * wq.w;
#pragma unroll
  for (int off = 32; off; off >>= 1) s += __shfl_xor(s, off, 64);
  __shared__ float red[4];
  if ((t & 63) == 0) red[t >> 6] = s;
  __syncthreads();
  if (t == 0) outp[row] = red[0] + red[1] + red[2] + red[3] + b2[0];
}

// ---------------------------------------------------------------------------
extern "C" void kernel_launch(void* const* d_in, const int* in_sizes, int n_in,
                              void* d_out, int out_size, void* d_ws,
                              size_t ws_size, hipStream_t stream) {
  const float* x_in = (const float*)d_in[0];
  const float* aln_g = (const float*)d_in[1];
  const float* aln_b = (const float*)d_in[2];
  const float* Wq_f = (const float*)d_in[3];
  const float* Wk_f = (const float*)d_in[4];
  const float* Wv_f = (const float*)d_in[5];
  const float* lnd_g = (const float*)d_in[6];
  const float* lnd_b = (const float*)d_in[7];
  const float* lnt_g = (const float*)d_in[8];
  const float* lnt_b = (const float*)d_in[9];
  const float* Wd1_f = (const float*)d_in[10];
  const float* bd1 = (const float*)d_in[11];
  const float* Wd2_f = (const float*)d_in[12];
  const float* bd2 = (const float*)d_in[13];
  const float* Wt1_f = (const float*)d_in[14];
  const float* bt1 = (const float*)d_in[15];
  const float* Wt2_f = (const float*)d_in[16];
  const float* bt2 = (const float*)d_in[17];
  const float* Wo1_f = (const float*)d_in[18];
  const float* bo1 = (const float*)d_in[19];
  const float* Wo2_f = (const float*)d_in[20];
  const float* bo2 = (const float*)d_in[21];

  const size_t R = 8192, D = 2048, HD = 1024;
  const size_t PLB = R * D * 2;               // bf16 plane: 32 MiB
  const size_t XF = R * D * 4;                // fp32 X: 64 MiB
  const size_t WALL = (3 * 3 * D * D + 4 * 2 * D * HD + HD * D) * 2;  // 108 MiB
  const size_t SLOT = D * D * 2;              // 8 MiB
  const bool planAll = ws_size >= XF + 4 * PLB + WALL;
  const bool xIsF32 = planAll || ws_size >= XF + 4 * PLB + SLOT;

  char* p = (char*)d_ws;
  float* Xf = nullptr;
  unsigned short* Xb = nullptr;
  if (xIsF32) { Xf = (float*)p; p += XF; } else { Xb = (unsigned short*)p; p += PLB; }
  unsigned short* XN = (unsigned short*)p; p += PLB;
  unsigned short* Qb = (unsigned short*)p; p += PLB;
  unsigned short* Kb = (unsigned short*)p; p += PLB;
  unsigned short* Vb = (unsigned short*)p; p += PLB;
  unsigned short* Warea = (unsigned short*)p;

  void* X = xIsF32 ? (void*)Xf : (void*)Xb;
  const int xres_mode = xIsF32 ? 1 : 2;
  unsigned short* H1 = Qb;
  unsigned short* DN = XN;
  unsigned short* TN = XN + R * HD;
  unsigned short* Hfin = Vb;

  auto cvt = [&](const float* src, unsigned short* dst, long n) {
    cvt_kernel<<<dim3((unsigned)(n / 1024)), dim3(256), 0, stream>>>(src, dst, n);
  };

  unsigned short* Wq_b = Warea;
  unsigned short* Wk_b = Wq_b + 3 * D * D;
  unsigned short* Wv_b = Wk_b + 3 * D * D;
  unsigned short* Wd1_b = Wv_b + 3 * D * D;
  unsigned short* Wd2_b = Wd1_b + 2 * D * HD;
  unsigned short* Wt1_b = Wd2_b + 2 * D * HD;
  unsigned short* Wt2_b = Wt1_b + 2 * D * HD;
  unsigned short* Wo1_b = Wt2_b + 2 * D * HD;
  if (planAll) {
    cvt(Wq_f, Wq_b, 3 * D * D);
    cvt(Wk_f, Wk_b, 3 * D * D);
    cvt(Wv_f, Wv_b, 3 * D * D);
    cvt(Wd1_f, Wd1_b, 2 * D * HD);
    cvt(Wd2_f, Wd2_b, 2 * D * HD);
    cvt(Wt1_f, Wt1_b, 2 * D * HD);
    cvt(Wt2_f, Wt2_b, 2 * D * HD);
    cvt(Wo1_f, Wo1_b, HD * D);
  }
  auto wbf = [&](const float* src_base, unsigned short* pre_base, size_t off,
                 size_t cnt) -> const unsigned short* {
    if (planAll) return pre_base + off;
    cvt(src_base + off, Warea, (long)cnt);
    return Warea;
  };

  auto gemm = [&](const unsigned short* A, int lda, const unsigned short* B,
                  int N, int K, void* C, int ldc, const float* bias,
                  const void* res, int res_mode, int ldres, int relu, int of32) {
    dim3 grid(N / 128, 8192 / 128);
    gemm_bt_kernel<<<grid, dim3(256), 0, stream>>>(
        A, lda, B, K, C, ldc, bias, res, res_mode, ldres, relu, of32);
  };

  for (int n = 0; n < 3; ++n) {
    const void* lin = (n == 0) ? (const void*)x_in : (const void*)X;
    const int lin_bf16 = (n == 0) ? 0 : (xIsF32 ? 0 : 1);
    ln_kernel<2048><<<8192, 256, 0, stream>>>(lin, lin_bf16, 2048,
                                              aln_g + n * D, aln_b + n * D, XN, 2048);
    const size_t wo = (size_t)n * D * D;
    gemm(XN, 2048, wbf(Wq_f, Wq_b, wo, D * D), 2048, 2048, Qb, 2048,
         nullptr, nullptr, 0, 0, 0, 0);
    gemm(XN, 2048, wbf(Wk_f, Wk_b, wo, D * D), 2048, 2048, Kb, 2048,
         nullptr, nullptr, 0, 0, 0, 0);
    gemm(XN, 2048, wbf(Wv_f, Wv_b, wo, D * D), 2048, 2048, Vb, 2048,
         nullptr, nullptr, 0, 0, 0, 0);
    // On the last attention layer also emit a bf16 copy of X for the final
    // head GEMM (replaces a separate cvt pass).
    attn_glue_kernel<<<8192, 512, 0, stream>>>(
        Qb, Kb, Vb, (n == 0) ? (const void*)x_in : (const void*)X,
        (n == 0) ? 0 : (xIsF32 ? 0 : 1), X, xIsF32 ? 0 : 1,
        (n == 2 && xIsF32) ? XN : nullptr);

    if (n < 2) {
      const size_t fo = (size_t)n * D * HD;
      ln_kernel<1024><<<8192, 256, 0, stream>>>(X, !xIsF32, 2048,
                                                lnd_g + n * HD, lnd_b + n * HD, DN, 1024);
      const void* Xt = xIsF32 ? (const void*)(Xf + HD) : (const void*)(Xb + HD);
      ln_kernel<1024><<<8192, 256, 0, stream>>>(Xt, !xIsF32, 2048,
                                                lnt_g + n * HD, lnt_b + n * HD, TN, 1024);
      void* Xd2 = X;
      void* Xt2 = xIsF32 ? (void*)(Xf + HD) : (void*)(Xb + HD);
      gemm(DN, 1024, wbf(Wd1_f, Wd1_b, fo, D * HD), 2048, 1024, H1, 2048,
           bd1 + n * D, nullptr, 0, 0, 1, 0);
      gemm(H1, 2048, wbf(Wd2_f, Wd2_b, fo, D * HD), 1024, 2048, Xd2, 2048,
           bd2 + n * HD, Xd2, xres_mode, 2048, 0, xIsF32 ? 1 : 0);
      gemm(TN, 1024, wbf(Wt1_f, Wt1_b, fo, D * HD), 2048, 1024, H1, 2048,
           bt1 + n * D, nullptr, 0, 0, 1, 0);
      gemm(H1, 2048, wbf(Wt2_f, Wt2_b, fo, D * HD), 1024, 2048, Xt2, 2048,
           bt2 + n * HD, Xt2, xres_mode, 2048, 0, xIsF32 ? 1 : 0);
    }
  }

  // final head: Hfin = relu(x @ Wo1^T + bo1); out = Hfin @ Wo2^T + bo2
  const unsigned short* Afin;
  if (xIsF32) {
    Afin = XN;  // bf16 copy written by the last attn_glue
  } else {
    Afin = Xb;
  }
  gemm(Afin, 2048, wbf(Wo1_f, Wo1_b, 0, HD * D), 1024, 2048, Hfin, 1024,
       bo1, nullptr, 0, 0, 1, 0);
  final_matvec_kernel<<<8192, 256, 0, stream>>>(Hfin, Wo2_f, bo2, (float*)d_out);
}

// Round 4
// 1329.944 us; speedup vs baseline: 1.5095x; 1.4913x over previous
//
#include <hip/hip_runtime.h>
#include <stdint.h>

// ---------------------------------------------------------------------------
// PairwiseAttentionLinear — fp32 in/out on device.
// Round 4: 256x256 8-phase GEMM template (T2 swizzle + T3/T4 counted vmcnt +
// T5 setprio), QKV fused (N=6144), FF2 as dual-GEMM. Legacy 128^2 kernel kept
// for Wo1 and as small-workspace fallback.
// ---------------------------------------------------------------------------

typedef __bf16 bf16x8 __attribute__((ext_vector_type(8)));
typedef float f32x4 __attribute__((ext_vector_type(4)));

static __device__ __forceinline__ float bf2f(unsigned short u) {
  unsigned int x = ((unsigned int)u) << 16;
  float f;
  __builtin_memcpy(&f, &x, 4);
  return f;
}
static __device__ __forceinline__ unsigned short f2bf(float f) {
  unsigned int x;
  __builtin_memcpy(&x, &f, 4);
  x += 0x7fffu + ((x >> 16) & 1u);  // RNE
  return (unsigned short)(x >> 16);
}

// global -> LDS direct copy, 16 B/lane; LDS base wave-uniform, HW adds lane*16
// (validated on HW by rounds 2->3 passing with uniform-base convention).
static __device__ __forceinline__ void gload_lds16(const void* g, void* l) {
  __builtin_amdgcn_global_load_lds(
      (const __attribute__((address_space(1))) unsigned int*)g,
      (__attribute__((address_space(3))) unsigned int*)l, 16, 0, 0);
}

// fp32 -> bf16, 4 elems/thread; n a multiple of 1024.
__global__ __launch_bounds__(256) void cvt_kernel(
    const float* __restrict__ in, unsigned short* __restrict__ out, long n) {
  const long i = ((long)blockIdx.x * 256 + threadIdx.x) * 4;
  if (i + 3 < n) {
    float4 f = *(const float4*)(in + i);
    *(ushort4*)(out + i) = make_ushort4(f2bf(f.x), f2bf(f.y), f2bf(f.z), f2bf(f.w));
  }
}

// ---------------------------------------------------------------------------
// gemm8: 256x256 tile, BK=64, 512 thr (8 waves, 2Mx4N), per-wave 128x64.
// C[i,j] = act(sum_k A[i,k]*B[j,k] + bias[j]) [+ C's prior f32 content].
// LDS 128 KiB: [buf][A 32K | B 32K] x2. T2 swizzle: byte ^= ((row&7)<<4),
// applied on the pre-swizzled global source (linear LDS dest, rule #21) and
// on ds_read addresses. 4 phases/K-tile, 2 barriers/phase, vmcnt(8) counted.
// dual: blocks with blockIdx.x >= gridDim.x/2 use the second operand set.
// ---------------------------------------------------------------------------
__global__ __launch_bounds__(512, 2) void gemm8_kernel(
    const unsigned short* __restrict__ A, int lda,
    const unsigned short* __restrict__ B, int K,
    void* __restrict__ Cp, int ldc, const float* __restrict__ bias,
    int relu, int out_f32, int resadd,
    const unsigned short* __restrict__ A2, const unsigned short* __restrict__ B2,
    void* __restrict__ C2p, const float* __restrict__ bias2, int dual) {
  extern __shared__ __align__(16) char smem[];  // 131072 B

  const int tid = threadIdx.x;
  const int lane = tid & 63;
  const int w = tid >> 6;
  const int wm = w >> 2;  // 0..1
  const int wn = w & 3;   // 0..3
  const long brow = (long)blockIdx.y * 256;

  const unsigned short* Ap = A;
  const unsigned short* Bp = B;
  const float* bi = bias;
  void* Cq = Cp;
  long bcol;
  if (dual && (int)blockIdx.x >= (int)(gridDim.x >> 1)) {
    Ap = A2; Bp = B2; bi = bias2; Cq = C2p;
    bcol = (long)(blockIdx.x - (gridDim.x >> 1)) * 256;
  } else {
    bcol = (long)blockIdx.x * 256;
  }

  const int NT = K >> 6;  // K-tiles of 64

  // ---- staging: one half-tile (128 rows x 64 cols bf16 = 16 KiB) = 2 issues
  auto stageA = [&](int t, int h) {
    char* lb = smem + (t & 1) * 65536 + h * 16384 + (tid & ~63) * 16;
    const unsigned short* g0 = Ap + (brow + h * 128) * (long)lda + (long)t * 64;
#pragma unroll
    for (int j = 0; j < 2; ++j) {
      const int u = j * 512 + tid;
      const int lrow = u >> 3;
      const int scb = ((u & 7) * 16) ^ ((lrow & 7) << 4);  // pre-swizzled src
      gload_lds16((const char*)(g0 + (long)lrow * lda) + scb, lb + j * 8192);
    }
  };
  auto stageB = [&](int t, int h) {
    char* lb = smem + (t & 1) * 65536 + 32768 + h * 16384 + (tid & ~63) * 16;
    const unsigned short* g0 = Bp + (bcol + h * 128) * (long)K + (long)t * 64;
#pragma unroll
    for (int j = 0; j < 2; ++j) {
      const int u = j * 512 + tid;
      const int lrow = u >> 3;
      const int scb = ((u & 7) * 16) ^ ((lrow & 7) << 4);
      gload_lds16((const char*)(g0 + (long)lrow * K) + scb, lb + j * 8192);
    }
  };

  f32x4 acc[8][4];
  const f32x4 fz = {0.f, 0.f, 0.f, 0.f};
#pragma unroll
  for (int m = 0; m < 8; ++m)
#pragma unroll
    for (int n = 0; n < 4; ++n) acc[m][n] = fz;

  const int frow = lane & 15;
  const int fkb = (lane >> 4) * 16;      // k-byte within 64-col row
  const int fswz = (lane & 7) << 4;      // T2 read-side swizzle

  // ---- prologue: stage tiles 0 and 1; wait tile 0 (8 loads of tile1 allowed)
  stageA(0, 0); stageA(0, 1); stageB(0, 0); stageB(0, 1);
  if (NT > 1) { stageA(1, 0); stageA(1, 1); stageB(1, 0); stageB(1, 1); }
  asm volatile("s_waitcnt vmcnt(8)");
  __builtin_amdgcn_s_barrier();

  for (int t = 0; t < NT; ++t) {
    char* Ab = smem + (t & 1) * 65536;
    char* Bb = Ab + 32768;

    // ---- phase 1: ds_read ALL fragments of tile t (24x ds_read_b128)
    bf16x8 af[8][2], bfv[4][2];
#pragma unroll
    for (int m = 0; m < 8; ++m)
#pragma unroll
      for (int kk = 0; kk < 2; ++kk)
        af[m][kk] = *(const bf16x8*)(Ab + (wm * 128 + m * 16 + frow) * 128 +
                                     ((kk * 64 + fkb) ^ fswz));
#pragma unroll
    for (int n = 0; n < 4; ++n)
#pragma unroll
      for (int kk = 0; kk < 2; ++kk)
        bfv[n][kk] = *(const bf16x8*)(Bb + (wn * 64 + n * 16 + frow) * 128 +
                                      ((kk * 64 + fkb) ^ fswz));
    __builtin_amdgcn_s_barrier();
    asm volatile("s_waitcnt lgkmcnt(0)");
    __builtin_amdgcn_sched_barrier(0);
    __builtin_amdgcn_s_setprio(1);
#pragma unroll
    for (int m = 0; m < 4; ++m)
#pragma unroll
      for (int n = 0; n < 2; ++n)
#pragma unroll
        for (int kk = 0; kk < 2; ++kk)
          acc[m][n] = __builtin_amdgcn_mfma_f32_16x16x32_bf16(
              af[m][kk], bfv[n][kk], acc[m][n], 0, 0, 0);
    __builtin_amdgcn_s_setprio(0);
    __builtin_amdgcn_s_barrier();

    // ---- phase 2: stage (t+2).A half0 ; MFMA quadrant (m0..3, n2..3)
    if (t + 2 < NT) stageA(t + 2, 0);
    __builtin_amdgcn_s_barrier();
    __builtin_amdgcn_s_setprio(1);
#pragma unroll
    for (int m = 0; m < 4; ++m)
#pragma unroll
      for (int n = 2; n < 4; ++n)
#pragma unroll
        for (int kk = 0; kk < 2; ++kk)
          acc[m][n] = __builtin_amdgcn_mfma_f32_16x16x32_bf16(
              af[m][kk], bfv[n][kk], acc[m][n], 0, 0, 0);
    __builtin_amdgcn_s_setprio(0);
    __builtin_amdgcn_s_barrier();

    // ---- phase 3: stage (t+2).B half0 ; MFMA quadrant (m4..7, n0..1)
    if (t + 2 < NT) stageB(t + 2, 0);
    __builtin_amdgcn_s_barrier();
    __builtin_amdgcn_s_setprio(1);
#pragma unroll
    for (int m = 4; m < 8; ++m)
#pragma unroll
      for (int n = 0; n < 2; ++n)
#pragma unroll
        for (int kk = 0; kk < 2; ++kk)
          acc[m][n] = __builtin_amdgcn_mfma_f32_16x16x32_bf16(
              af[m][kk], bfv[n][kk], acc[m][n], 0, 0, 0);
    __builtin_amdgcn_s_setprio(0);
    __builtin_amdgcn_s_barrier();

    // ---- phase 4: stage (t+2).A/B half1 ; counted vmcnt ; quadrant (m4..7,n2..3)
    if (t + 2 < NT) {
      stageA(t + 2, 1); stageB(t + 2, 1);
      asm volatile("s_waitcnt vmcnt(8)");   // tile t+1 fully landed
    } else {
      asm volatile("s_waitcnt vmcnt(0)");   // tail drain
    }
    __builtin_amdgcn_s_barrier();
    __builtin_amdgcn_s_setprio(1);
#pragma unroll
    for (int m = 4; m < 8; ++m)
#pragma unroll
      for (int n = 2; n < 4; ++n)
#pragma unroll
        for (int kk = 0; kk < 2; ++kk)
          acc[m][n] = __builtin_amdgcn_mfma_f32_16x16x32_bf16(
              af[m][kk], bfv[n][kk], acc[m][n], 0, 0, 0);
    __builtin_amdgcn_s_setprio(0);
    __builtin_amdgcn_s_barrier();
  }

  // ---- epilogue: C/D layout col=lane&15, row=(lane>>4)*4+reg [m89]
  const long rb0 = brow + wm * 128 + (lane >> 4) * 4;
  const long cb0 = bcol + wn * 64 + (lane & 15);
#pragma unroll
  for (int m = 0; m < 8; ++m) {
#pragma unroll
    for (int n = 0; n < 4; ++n) {
      const long col = cb0 + n * 16;
      const float bv = bi ? bi[col] : 0.f;
#pragma unroll
      for (int j = 0; j < 4; ++j) {
        const long r = rb0 + m * 16 + j;
        float v = acc[m][n][j] + bv;
        if (relu) v = fmaxf(v, 0.f);
        if (out_f32) {
          float* cp = (float*)Cq + r * (long)ldc + col;
          if (resadd) v += *cp;
          *cp = v;
        } else {
          ((unsigned short*)Cq)[r * (long)ldc + col] = f2bf(v);
        }
      }
    }
  }
}

// ---------------------------------------------------------------------------
// Legacy 128x128 GEMM (round-3, validated) — used for Wo1 + fallback path.
// ---------------------------------------------------------------------------
__global__ __launch_bounds__(256) void gemm_bt_kernel(
    const unsigned short* __restrict__ A, int lda,
    const unsigned short* __restrict__ B, int K,
    void* __restrict__ Cp, int ldc,
    const float* __restrict__ bias,
    const void* __restrict__ res, int res_mode, int ldres,
    int relu, int out_f32) {
  __shared__ __align__(16) unsigned short As[128 * 32];
  __shared__ __align__(16) unsigned short Bs[128 * 32];

  const int t = threadIdx.x;
  const int lane = t & 63;
  const int w = t >> 6;
  const int wr = (w >> 1) * 64;
  const int wc = (w & 1) * 64;
  const long brow = (long)blockIdx.y * 128;
  const long bcol = (long)blockIdx.x * 128;

  const int srow = lane >> 2;
  const int scol = (lane & 3) * 8;
  const unsigned short* Ab = A + (brow + w * 32 + srow) * (long)lda + scol;
  const unsigned short* Bb = B + (bcol + w * 32 + srow) * (long)K + scol;
  unsigned short* Asb = &As[(w * 32) * 32];
  unsigned short* Bsb = &Bs[(w * 32) * 32];

  f32x4 acc[4][4];
  const f32x4 fzero = {0.f, 0.f, 0.f, 0.f};
#pragma unroll
  for (int m = 0; m < 4; ++m)
#pragma unroll
    for (int n = 0; n < 4; ++n) acc[m][n] = fzero;

  const int fr = lane & 15;
  const int fk = (lane >> 4) * 8;

  for (int kt = 0; kt < K; kt += 32) {
    gload_lds16(Ab + kt, Asb);
    gload_lds16(Ab + 16 * (long)lda + kt, Asb + 16 * 32);
    gload_lds16(Bb + kt, Bsb);
    gload_lds16(Bb + 16 * (long)K + kt, Bsb + 16 * 32);
    __syncthreads();

    bf16x8 af[4], bfv[4];
#pragma unroll
    for (int m = 0; m < 4; ++m)
      af[m] = *(const bf16x8*)&As[(wr + m * 16 + fr) * 32 + fk];
#pragma unroll
    for (int n = 0; n < 4; ++n)
      bfv[n] = *(const bf16x8*)&Bs[(wc + n * 16 + fr) * 32 + fk];
#pragma unroll
    for (int m = 0; m < 4; ++m)
#pragma unroll
      for (int n = 0; n < 4; ++n)
        acc[m][n] = __builtin_amdgcn_mfma_f32_16x16x32_bf16(af[m], bfv[n],
                                                            acc[m][n], 0, 0, 0);
    __syncthreads();
  }

  const long rbase = brow + wr + (lane >> 4) * 4;
#pragma unroll
  for (int m = 0; m < 4; ++m) {
#pragma unroll
    for (int n = 0; n < 4; ++n) {
      const long col = bcol + wc + n * 16 + fr;
      const float bv = bias ? bias[col] : 0.f;
#pragma unroll
      for (int j = 0; j < 4; ++j) {
        const long r = rbase + m * 16 + j;
        float v = acc[m][n][j] + bv;
        if (relu) v = fmaxf(v, 0.f);
        if (res_mode == 1)
          v += ((const float*)res)[r * (long)ldres + col];
        else if (res_mode == 2)
          v += bf2f(((const unsigned short*)res)[r * (long)ldres + col]);
        if (out_f32)
          ((float*)Cp)[r * (long)ldc + col] = v;
        else
          ((unsigned short*)Cp)[r * (long)ldc + col] = f2bf(v);
      }
    }
  }
}

// ---------------------------------------------------------------------------
// LayerNorm (one 256-thread block per row); in fp32 or bf16; out bf16.
// ---------------------------------------------------------------------------
template <int L>
__global__ __launch_bounds__(256) void ln_kernel(
    const void* __restrict__ inp, int in_bf16, int ldin,
    const float* __restrict__ g, const float* __restrict__ b,
    unsigned short* __restrict__ outp, int ldout) {
  constexpr int VEC = L / 256;
  const long row = blockIdx.x;
  const int t = threadIdx.x;
  float v[VEC];
  if (in_bf16) {
    const unsigned short* p = (const unsigned short*)inp + row * (long)ldin + t * VEC;
#pragma unroll
    for (int i = 0; i < VEC; i += 4) {
      ushort4 u = *(const ushort4*)(p + i);
      v[i] = bf2f(u.x); v[i + 1] = bf2f(u.y); v[i + 2] = bf2f(u.z); v[i + 3] = bf2f(u.w);
    }
  } else {
    const float* p = (const float*)inp + row * (long)ldin + t * VEC;
#pragma unroll
    for (int i = 0; i < VEC; i += 4) {
      float4 f = *(const float4*)(p + i);
      v[i] = f.x; v[i + 1] = f.y; v[i + 2] = f.z; v[i + 3] = f.w;
    }
  }
  float s = 0.f, sq = 0.f;
#pragma unroll
  for (int i = 0; i < VEC; ++i) { s += v[i]; sq += v[i] * v[i]; }
#pragma unroll
  for (int off = 32; off; off >>= 1) {
    s += __shfl_xor(s, off, 64);
    sq += __shfl_xor(sq, off, 64);
  }
  __shared__ float red[8];
  if ((t & 63) == 0) { red[t >> 6] = s; red[4 + (t >> 6)] = sq; }
  __syncthreads();
  s = red[0] + red[1] + red[2] + red[3];
  sq = red[4] + red[5] + red[6] + red[7];
  const float mean = s * (1.f / L);
  const float var = sq * (1.f / L) - mean * mean;
  const float rstd = rsqrtf(var + 1e-6f);
  unsigned short* op = outp + row * (long)ldout + t * VEC;
  const float* gp = g + t * VEC;
  const float* bp = b + t * VEC;
#pragma unroll
  for (int i = 0; i < VEC; i += 4) {
    float4 gg = *(const float4*)(gp + i);
    float4 bb = *(const float4*)(bp + i);
    *(ushort4*)(op + i) = make_ushort4(
        f2bf((v[i + 0] - mean) * rstd * gg.x + bb.x),
        f2bf((v[i + 1] - mean) * rstd * gg.y + bb.y),
        f2bf((v[i + 2] - mean) * rstd * gg.z + bb.z),
        f2bf((v[i + 3] - mean) * rstd * gg.w + bb.w));
  }
}

// ---------------------------------------------------------------------------
// Pairwise attention glue; Q/K/V strides = ld (2048 legacy, 6144 fused).
// ---------------------------------------------------------------------------
__global__ __launch_bounds__(512) void attn_glue_kernel(
    const unsigned short* __restrict__ Q, const unsigned short* __restrict__ Kq,
    const unsigned short* __restrict__ V, int ld, const void* __restrict__ Xres,
    int res_bf16, void* __restrict__ Xout, int out_bf16,
    unsigned short* __restrict__ Xout_bf) {
  const long row = blockIdx.x;
  const int h = threadIdx.x >> 6;
  const int lane = threadIdx.x & 63;
  const long qbase = row * (long)ld + h * 256;
  const long xbase = row * 2048 + h * 256;
  const int d = lane * 2;

  ushort2 q0 = *(const ushort2*)&Q[qbase + d];
  ushort2 q1 = *(const ushort2*)&Q[qbase + 128 + d];
  ushort2 k0 = *(const ushort2*)&Kq[qbase + d];
  ushort2 k1 = *(const ushort2*)&Kq[qbase + 128 + d];
  ushort2 v0 = *(const ushort2*)&V[qbase + d];
  ushort2 v1 = *(const ushort2*)&V[qbase + 128 + d];

  const float q0x = bf2f(q0.x), q0y = bf2f(q0.y);
  const float q1x = bf2f(q1.x), q1y = bf2f(q1.y);
  const float k0x = bf2f(k0.x), k0y = bf2f(k0.y);
  const float k1x = bf2f(k1.x), k1y = bf2f(k1.y);

  float s00 = q0x * k0x + q0y * k0y;
  float s01 = q0x * k1x + q0y * k1y;
  float s10 = q1x * k0x + q1y * k0y;
  float s11 = q1x * k1x + q1y * k1y;
#pragma unroll
  for (int off = 32; off; off >>= 1) {
    s00 += __shfl_xor(s00, off, 64);
    s01 += __shfl_xor(s01, off, 64);
    s10 += __shfl_xor(s10, off, 64);
    s11 += __shfl_xor(s11, off, 64);
  }
  const float SC = 0.088388347648318447f;  // 1/sqrt(128)
  s00 *= SC; s01 *= SC; s10 *= SC; s11 *= SC;
  const float m0 = fmaxf(s00, s01), m1 = fmaxf(s10, s11);
  const float e00 = __expf(s00 - m0), e01 = __expf(s01 - m0);
  const float e10 = __expf(s10 - m1), e11 = __expf(s11 - m1);
  const float i0 = 1.f / (e00 + e01), i1 = 1.f / (e10 + e11);
  const float a00 = e00 * i0, a01 = e01 * i0;
  const float a10 = e10 * i1, a11 = e11 * i1;

  const float v0x = bf2f(v0.x), v0y = bf2f(v0.y);
  const float v1x = bf2f(v1.x), v1y = bf2f(v1.y);
  float o0x = a00 * v0x + a01 * v1x, o0y = a00 * v0y + a01 * v1y;
  float o1x = a10 * v0x + a11 * v1x, o1y = a10 * v0y + a11 * v1y;

  if (res_bf16) {
    const unsigned short* xr = (const unsigned short*)Xres + xbase;
    ushort2 ra = *(const ushort2*)&xr[d];
    ushort2 rb = *(const ushort2*)&xr[128 + d];
    o0x += bf2f(ra.x); o0y += bf2f(ra.y); o1x += bf2f(rb.x); o1y += bf2f(rb.y);
  } else {
    const float* xr = (const float*)Xres + xbase;
    float2 ra = *(const float2*)&xr[d];
    float2 rb = *(const float2*)&xr[128 + d];
    o0x += ra.x; o0y += ra.y; o1x += rb.x; o1y += rb.y;
  }
  if (out_bf16) {
    unsigned short* xo = (unsigned short*)Xout + xbase;
    *(ushort2*)&xo[d] = make_ushort2(f2bf(o0x), f2bf(o0y));
    *(ushort2*)&xo[128 + d] = make_ushort2(f2bf(o1x), f2bf(o1y));
  } else {
    float* xo = (float*)Xout + xbase;
    *(float2*)&xo[d] = make_float2(o0x, o0y);
    *(float2*)&xo[128 + d] = make_float2(o1x, o1y);
  }
  if (Xout_bf) {
    unsigned short* xb = Xout_bf + xbase;
    *(ushort2*)&xb[d] = make_ushort2(f2bf(o0x), f2bf(o0y));
    *(ushort2*)&xb[128 + d] = make_ushort2(f2bf(o1x), f2bf(o1y));
  }
}

// out[row] = dot(H[row,0:1024] (bf16), w (f32)) + b ; fp32 out.
__global__ __launch_bounds__(256) void final_matvec_kernel(
    const unsigned short* __restrict__ Hm, const float* __restrict__ wv,
    const float* __restrict__ b2, float* __restrict__ outp) {
  const long row = blockIdx.x;
  const int t = threadIdx.x;
  ushort4 hv = *(const ushort4*)&Hm[row * 1024 + t * 4];
  float4 wq = *(const float4*)&wv[t * 4];
  float s = bf2f(hv.x) * wq.x + bf2f(hv.y) * wq.y +
            bf2f(hv.z) * wq.z + bf2f(hv.w) * wq.w;
#pragma unroll
  for (int off = 32; off; off >>= 1) s += __shfl_xor(s, off, 64);
  __shared__ float red[4];
  if ((t & 63) == 0) red[t >> 6] = s;
  __syncthreads();
  if (t == 0) outp[row] = red[0] + red[1] + red[2] + red[3] + b2[0];
}

// ---------------------------------------------------------------------------
extern "C" void kernel_launch(void* const* d_in, const int* in_sizes, int n_in,
                              void* d_out, int out_size, void* d_ws,
                              size_t ws_size, hipStream_t stream) {
  const float* x_in = (const float*)d_in[0];
  const float* aln_g = (const float*)d_in[1];
  const float* aln_b = (const float*)d_in[2];
  const float* Wq_f = (const float*)d_in[3];
  const float* Wk_f = (const float*)d_in[4];
  const float* Wv_f = (const float*)d_in[5];
  const float* lnd_g = (const float*)d_in[6];
  const float* lnd_b = (const float*)d_in[7];
  const float* lnt_g = (const float*)d_in[8];
  const float* lnt_b = (const float*)d_in[9];
  const float* Wd1_f = (const float*)d_in[10];
  const float* bd1 = (const float*)d_in[11];
  const float* Wd2_f = (const float*)d_in[12];
  const float* bd2 = (const float*)d_in[13];
  const float* Wt1_f = (const float*)d_in[14];
  const float* bt1 = (const float*)d_in[15];
  const float* Wt2_f = (const float*)d_in[16];
  const float* bt2 = (const float*)d_in[17];
  const float* Wo1_f = (const float*)d_in[18];
  const float* bo1 = (const float*)d_in[19];
  const float* Wo2_f = (const float*)d_in[20];
  const float* bo2 = (const float*)d_in[21];

  const size_t R = 8192, D = 2048, HD = 1024;
  const size_t DD = D * D;
  const size_t WALL = (3 * 3 * DD + 4 * 2 * D * HD + HD * D) * 2;  // 108 MiB
  const size_t SLOT = 3 * DD * 2;                                  // 24 MiB
  const size_t ACT = R * D * 4 + R * D * 2 + R * 6144 * 2;         // 192 MiB

  auto cvt = [&](const float* src, unsigned short* dst, long n) {
    cvt_kernel<<<dim3((unsigned)(n / 1024)), dim3(256), 0, stream>>>(src, dst, n);
  };

  if (ws_size >= ACT + SLOT) {
    // ===================== fast path (8-phase GEMMs) =====================
    const bool planAll = ws_size >= ACT + WALL;
    hipFuncSetAttribute(reinterpret_cast<const void*>(gemm8_kernel),
                        hipFuncAttributeMaxDynamicSharedMemorySize, 131072);

    char* p = (char*)d_ws;
    float* Xf = (float*)p; p += R * D * 4;
    unsigned short* XN = (unsigned short*)p; p += R * D * 2;
    unsigned short* QKVb = (unsigned short*)p; p += R * 6144 * 2;
    unsigned short* Warea = (unsigned short*)p;

    unsigned short* H1d = QKVb;
    unsigned short* H1t = QKVb + R * 2048;
    unsigned short* Hfin = QKVb + R * 4096;
    unsigned short* DN = XN;
    unsigned short* TN = XN + R * HD;

    // weight area layout (planAll): [n][3]{q,k,v} DD each, then Wd1,Wt1,Wd2,
    // Wt2 (2*D*HD each), Wo1 (HD*D)
    unsigned short* Wqkv_b = Warea;
    unsigned short* Wd1_b = Wqkv_b + 9 * DD;
    unsigned short* Wt1_b = Wd1_b + 2 * D * HD;
    unsigned short* Wd2_b = Wt1_b + 2 * D * HD;
    unsigned short* Wt2_b = Wd2_b + 2 * D * HD;
    unsigned short* Wo1_b = Wt2_b + 2 * D * HD;
    if (planAll) {
      for (int n = 0; n < 3; ++n) {
        cvt(Wq_f + n * DD, Wqkv_b + n * 3 * DD + 0 * DD, DD);
        cvt(Wk_f + n * DD, Wqkv_b + n * 3 * DD + 1 * DD, DD);
        cvt(Wv_f + n * DD, Wqkv_b + n * 3 * DD + 2 * DD, DD);
      }
      cvt(Wd1_f, Wd1_b, 2 * D * HD);
      cvt(Wt1_f, Wt1_b, 2 * D * HD);
      cvt(Wd2_f, Wd2_b, 2 * D * HD);
      cvt(Wt2_f, Wt2_b, 2 * D * HD);
      cvt(Wo1_f, Wo1_b, HD * D);
    }

    auto gemm8 = [&](const unsigned short* A, int lda, const unsigned short* B,
                     int N, int K, void* C, int ldc, const float* bias,
                     int relu, int of32, int resadd, const unsigned short* A2,
                     const unsigned short* B2, void* C2, const float* bias2) {
      dim3 grid(N / 256, 32);
      gemm8_kernel<<<grid, dim3(512), 131072, stream>>>(
          A, lda, B, K, C, ldc, bias, relu, of32, resadd, A2, B2, C2, bias2,
          A2 != nullptr);
    };

    for (int n = 0; n < 3; ++n) {
      ln_kernel<2048><<<8192, 256, 0, stream>>>(
          (n == 0) ? (const void*)x_in : (const void*)Xf, 0, 2048,
          aln_g + n * D, aln_b + n * D, XN, 2048);
      // fused QKV GEMM: N=6144
      const unsigned short* Wqkv;
      if (planAll) {
        Wqkv = Wqkv_b + (size_t)n * 3 * DD;
      } else {
        cvt(Wq_f + n * DD, Warea + 0 * DD, DD);
        cvt(Wk_f + n * DD, Warea + 1 * DD, DD);
        cvt(Wv_f + n * DD, Warea + 2 * DD, DD);
        Wqkv = Warea;
      }
      gemm8(XN, 2048, Wqkv, 6144, 2048, QKVb, 6144, nullptr, 0, 0, 0,
            nullptr, nullptr, nullptr, nullptr);
      attn_glue_kernel<<<8192, 512, 0, stream>>>(
          QKVb, QKVb + 2048, QKVb + 4096, 6144,
          (n == 0) ? (const void*)x_in : (const void*)Xf, 0, Xf, 0,
          (n == 2) ? XN : nullptr);

      if (n < 2) {
        const size_t fo = (size_t)n * D * HD;
        ln_kernel<1024><<<8192, 256, 0, stream>>>(Xf, 0, 2048, lnd_g + n * HD,
                                                  lnd_b + n * HD, DN, 1024);
        ln_kernel<1024><<<8192, 256, 0, stream>>>(Xf + HD, 0, 2048,
                                                  lnt_g + n * HD,
                                                  lnt_b + n * HD, TN, 1024);
        const unsigned short *w1d, *w1t, *w2d, *w2t;
        if (planAll) {
          w1d = Wd1_b + fo; w1t = Wt1_b + fo; w2d = Wd2_b + fo; w2t = Wt2_b + fo;
        } else {
          cvt(Wd1_f + fo, Warea + 0 * D * HD, D * HD);
          cvt(Wt1_f + fo, Warea + 1 * D * HD, D * HD);
          cvt(Wd2_f + fo, Warea + 2 * D * HD, D * HD);
          cvt(Wt2_f + fo, Warea + 3 * D * HD, D * HD);
          w1d = Warea; w1t = Warea + D * HD; w2d = Warea + 2 * D * HD;
          w2t = Warea + 3 * D * HD;
        }
        gemm8(DN, 1024, w1d, 2048, 1024, H1d, 2048, bd1 + n * D, 1, 0, 0,
              nullptr, nullptr, nullptr, nullptr);
        gemm8(TN, 1024, w1t, 2048, 1024, H1t, 2048, bt1 + n * D, 1, 0, 0,
              nullptr, nullptr, nullptr, nullptr);
        // dual down-proj: d-half -> X[:, :1024], t-half -> X[:, 1024:]
        gemm8(H1d, 2048, w2d, 2048, 2048, Xf, 2048, bd2 + n * HD, 0, 1, 1,
              H1t, w2t, Xf + HD, bt2 + n * HD);
      }
    }

    // final head (legacy kernels): Hfin = relu(Xbf @ Wo1^T + bo1)
    const unsigned short* Wo1p;
    if (planAll) {
      Wo1p = Wo1_b;
    } else {
      cvt(Wo1_f, Warea, HD * D);
      Wo1p = Warea;
    }
    gemm_bt_kernel<<<dim3(1024 / 128, 8192 / 128), dim3(256), 0, stream>>>(
        XN, 2048, Wo1p, 2048, Hfin, 1024, bo1, nullptr, 0, 0, 1, 0);
    final_matvec_kernel<<<8192, 256, 0, stream>>>(Hfin, Wo2_f, bo2,
                                                  (float*)d_out);
    return;
  }

  // ======================= legacy fallback path =======================
  const size_t PLB = R * D * 2;
  const size_t XFZ = R * D * 4;
  const size_t SLOT1 = DD * 2;
  const bool planAll = ws_size >= XFZ + 4 * PLB + WALL;
  const bool xIsF32 = planAll || ws_size >= XFZ + 4 * PLB + SLOT1;

  char* p = (char*)d_ws;
  float* Xf = nullptr;
  unsigned short* Xb = nullptr;
  if (xIsF32) { Xf = (float*)p; p += XFZ; } else { Xb = (unsigned short*)p; p += PLB; }
  unsigned short* XN = (unsigned short*)p; p += PLB;
  unsigned short* Qb = (unsigned short*)p; p += PLB;
  unsigned short* Kb = (unsigned short*)p; p += PLB;
  unsigned short* Vb = (unsigned short*)p; p += PLB;
  unsigned short* Warea = (unsigned short*)p;

  void* X = xIsF32 ? (void*)Xf : (void*)Xb;
  const int xres_mode = xIsF32 ? 1 : 2;
  unsigned short* H1 = Qb;
  unsigned short* DN = XN;
  unsigned short* TN = XN + R * HD;
  unsigned short* Hfin = Vb;

  unsigned short* Wq_b = Warea;
  unsigned short* Wk_b = Wq_b + 3 * DD;
  unsigned short* Wv_b = Wk_b + 3 * DD;
  unsigned short* Wd1_b = Wv_b + 3 * DD;
  unsigned short* Wd2_b = Wd1_b + 2 * D * HD;
  unsigned short* Wt1_b = Wd2_b + 2 * D * HD;
  unsigned short* Wt2_b = Wt1_b + 2 * D * HD;
  unsigned short* Wo1_b = Wt2_b + 2 * D * HD;
  if (planAll) {
    cvt(Wq_f, Wq_b, 3 * DD);
    cvt(Wk_f, Wk_b, 3 * DD);
    cvt(Wv_f, Wv_b, 3 * DD);
    cvt(Wd1_f, Wd1_b, 2 * D * HD);
    cvt(Wd2_f, Wd2_b, 2 * D * HD);
    cvt(Wt1_f, Wt1_b, 2 * D * HD);
    cvt(Wt2_f, Wt2_b, 2 * D * HD);
    cvt(Wo1_f, Wo1_b, HD * D);
  }
  auto wbf = [&](const float* src_base, unsigned short* pre_base, size_t off,
                 size_t cnt) -> const unsigned short* {
    if (planAll) return pre_base + off;
    cvt(src_base + off, Warea, (long)cnt);
    return Warea;
  };
  auto gemm = [&](const unsigned short* A, int lda, const unsigned short* B,
                  int N, int K, void* C, int ldc, const float* bias,
                  const void* res, int res_mode, int ldres, int relu, int of32) {
    dim3 grid(N / 128, 8192 / 128);
    gemm_bt_kernel<<<grid, dim3(256), 0, stream>>>(
        A, lda, B, K, C, ldc, bias, res, res_mode, ldres, relu, of32);
  };

  for (int n = 0; n < 3; ++n) {
    const void* lin = (n == 0) ? (const void*)x_in : (const void*)X;
    const int lin_bf16 = (n == 0) ? 0 : (xIsF32 ? 0 : 1);
    ln_kernel<2048><<<8192, 256, 0, stream>>>(lin, lin_bf16, 2048,
                                              aln_g + n * D, aln_b + n * D, XN, 2048);
    const size_t wo = (size_t)n * DD;
    gemm(XN, 2048, wbf(Wq_f, Wq_b, wo, DD), 2048, 2048, Qb, 2048,
         nullptr, nullptr, 0, 0, 0, 0);
    gemm(XN, 2048, wbf(Wk_f, Wk_b, wo, DD), 2048, 2048, Kb, 2048,
         nullptr, nullptr, 0, 0, 0, 0);
    gemm(XN, 2048, wbf(Wv_f, Wv_b, wo, DD), 2048, 2048, Vb, 2048,
         nullptr, nullptr, 0, 0, 0, 0);
    attn_glue_kernel<<<8192, 512, 0, stream>>>(
        Qb, Kb, Vb, 2048, (n == 0) ? (const void*)x_in : (const void*)X,
        (n == 0) ? 0 : (xIsF32 ? 0 : 1), X, xIsF32 ? 0 : 1,
        (n == 2 && xIsF32) ? XN : nullptr);

    if (n < 2) {
      const size_t fo = (size_t)n * D * HD;
      ln_kernel<1024><<<8192, 256, 0, stream>>>(X, !xIsF32, 2048,
                                                lnd_g + n * HD, lnd_b + n * HD, DN, 1024);
      const void* Xt = xIsF32 ? (const void*)(Xf + HD) : (const void*)(Xb + HD);
      ln_kernel<1024><<<8192, 256, 0, stream>>>(Xt, !xIsF32, 2048,
                                                lnt_g + n * HD, lnt_b + n * HD, TN, 1024);
      void* Xd2 = X;
      void* Xt2 = xIsF32 ? (void*)(Xf + HD) : (void*)(Xb + HD);
      gemm(DN, 1024, wbf(Wd1_f, Wd1_b, fo, D * HD), 2048, 1024, H1, 2048,
           bd1 + n * D, nullptr, 0, 0, 1, 0);
      gemm(H1, 2048, wbf(Wd2_f, Wd2_b, fo, D * HD), 1024, 2048, Xd2, 2048,
           bd2 + n * HD, Xd2, xres_mode, 2048, 0, xIsF32 ? 1 : 0);
      gemm(TN, 1024, wbf(Wt1_f, Wt1_b, fo, D * HD), 2048, 1024, H1, 2048,
           bt1 + n * D, nullptr, 0, 0, 1, 0);
      gemm(H1, 2048, wbf(Wt2_f, Wt2_b, fo, D * HD), 1024, 2048, Xt2, 2048,
           bt2 + n * HD, Xt2, xres_mode, 2048, 0, xIsF32 ? 1 : 0);
    }
  }

  const unsigned short* Afin = xIsF32 ? XN : Xb;
  gemm(Afin, 2048, wbf(Wo1_f, Wo1_b, 0, HD * D), 1024, 2048, Hfin, 1024,
       bo1, nullptr, 0, 0, 1, 0);
  final_matvec_kernel<<<8192, 256, 0, stream>>>(Hfin, Wo2_f, bo2, (float*)d_out);
}

// Round 5
// 1312.526 us; speedup vs baseline: 1.5295x; 1.0133x over previous
//
#include <hip/hip_runtime.h>
#include <stdint.h>

// ---------------------------------------------------------------------------
// PairwiseAttentionLinear — fp32 in/out on device.
// Round 5: gemm8 K-loop restructured to true m201 per-phase interleave
// (ds_read subtile ∥ stage ∥ MFMA per phase), counted vmcnt(8), T2 swizzle,
// T5 setprio. QKV fused (N=6144); FF1 + FF2 dual-GEMMs; Wo1 via gemm8.
// ---------------------------------------------------------------------------

typedef __bf16 bf16x8 __attribute__((ext_vector_type(8)));
typedef float f32x4 __attribute__((ext_vector_type(4)));

static __device__ __forceinline__ float bf2f(unsigned short u) {
  unsigned int x = ((unsigned int)u) << 16;
  float f;
  __builtin_memcpy(&f, &x, 4);
  return f;
}
static __device__ __forceinline__ unsigned short f2bf(float f) {
  unsigned int x;
  __builtin_memcpy(&x, &f, 4);
  x += 0x7fffu + ((x >> 16) & 1u);  // RNE
  return (unsigned short)(x >> 16);
}

static __device__ __forceinline__ void gload_lds16(const void* g, void* l) {
  __builtin_amdgcn_global_load_lds(
      (const __attribute__((address_space(1))) unsigned int*)g,
      (__attribute__((address_space(3))) unsigned int*)l, 16, 0, 0);
}

__global__ __launch_bounds__(256) void cvt_kernel(
    const float* __restrict__ in, unsigned short* __restrict__ out, long n) {
  const long i = ((long)blockIdx.x * 256 + threadIdx.x) * 4;
  if (i + 3 < n) {
    float4 f = *(const float4*)(in + i);
    *(ushort4*)(out + i) = make_ushort4(f2bf(f.x), f2bf(f.y), f2bf(f.z), f2bf(f.w));
  }
}

// ---------------------------------------------------------------------------
// gemm8: 256x256 tile, BK=64, 512 thr (8 waves, 2Mx4N), per-wave 128x64.
// LDS 128 KiB: [buf][A 32K | B 32K] x2 (prefetch distance 2).
// T2 swizzle byte ^= ((row&7)<<4): pre-swizzled global source (linear LDS
// dest, rule #21) + swizzled ds_read. 4 phases/K-tile:
//   A: read afL,bfvL            ; MFMA Q0 (m0-3,n0-1)
//   B: read bfvH                ; MFMA Q1 (m0-3,n2-3)
//   C: read afH ; stage B(t+2)  ; MFMA Q2 (m4-7,n0-1)   [B-reads done @end-B]
//   D: stage A(t+2); vmcnt(8)   ; MFMA Q3 (m4-7,n2-3)   [A-reads done @end-C]
// dual: blocks with blockIdx.x >= gridDim.x/2 use the second operand set.
// ---------------------------------------------------------------------------
__global__ __launch_bounds__(512, 2) void gemm8_kernel(
    const unsigned short* __restrict__ A, int lda,
    const unsigned short* __restrict__ B, int K,
    void* __restrict__ Cp, int ldc, const float* __restrict__ bias,
    int relu, int out_f32, int resadd,
    const unsigned short* __restrict__ A2, const unsigned short* __restrict__ B2,
    void* __restrict__ C2p, const float* __restrict__ bias2, int dual) {
  extern __shared__ __align__(16) char smem[];  // 131072 B

  const int tid = threadIdx.x;
  const int lane = tid & 63;
  const int w = tid >> 6;
  const int wm = w >> 2;  // 0..1
  const int wn = w & 3;   // 0..3
  const long brow = (long)blockIdx.y * 256;

  const unsigned short* Ap = A;
  const unsigned short* Bp = B;
  const float* bi = bias;
  void* Cq = Cp;
  long bcol;
  if (dual && (int)blockIdx.x >= (int)(gridDim.x >> 1)) {
    Ap = A2; Bp = B2; bi = bias2; Cq = C2p;
    bcol = (long)(blockIdx.x - (gridDim.x >> 1)) * 256;
  } else {
    bcol = (long)blockIdx.x * 256;
  }

  const int NT = K >> 6;  // K-tiles of 64

  // staging: one half-tile (128 rows x 64 cols bf16 = 16 KiB) = 2 issues/thread
  auto stageA = [&](int t, int h) {
    char* lb = smem + (t & 1) * 65536 + h * 16384 + (tid & ~63) * 16;
    const unsigned short* g0 = Ap + (brow + h * 128) * (long)lda + (long)t * 64;
#pragma unroll
    for (int j = 0; j < 2; ++j) {
      const int u = j * 512 + tid;
      const int lrow = u >> 3;
      const int scb = ((u & 7) * 16) ^ ((lrow & 7) << 4);  // pre-swizzled src
      gload_lds16((const char*)(g0 + (long)lrow * lda) + scb, lb + j * 8192);
    }
  };
  auto stageB = [&](int t, int h) {
    char* lb = smem + (t & 1) * 65536 + 32768 + h * 16384 + (tid & ~63) * 16;
    const unsigned short* g0 = Bp + (bcol + h * 128) * (long)K + (long)t * 64;
#pragma unroll
    for (int j = 0; j < 2; ++j) {
      const int u = j * 512 + tid;
      const int lrow = u >> 3;
      const int scb = ((u & 7) * 16) ^ ((lrow & 7) << 4);
      gload_lds16((const char*)(g0 + (long)lrow * K) + scb, lb + j * 8192);
    }
  };

  f32x4 acc[8][4];
  const f32x4 fz = {0.f, 0.f, 0.f, 0.f};
#pragma unroll
  for (int m = 0; m < 8; ++m)
#pragma unroll
    for (int n = 0; n < 4; ++n) acc[m][n] = fz;

  const int frow = lane & 15;
  const int fkb = (lane >> 4) * 16;      // k-byte within 64-col row
  const int fswz = (lane & 7) << 4;      // T2 read-side swizzle

  // prologue: stage tiles 0,1 fully; wait tile 0 landed (tile 1 in flight)
  stageA(0, 0); stageA(0, 1); stageB(0, 0); stageB(0, 1);
  if (NT > 1) { stageA(1, 0); stageA(1, 1); stageB(1, 0); stageB(1, 1); }
  asm volatile("s_waitcnt vmcnt(8)");
  __builtin_amdgcn_s_barrier();

  for (int t = 0; t < NT; ++t) {
    char* Ab = smem + (t & 1) * 65536;
    char* Bb = Ab + 32768;
    bf16x8 afL[4][2], afH[4][2], bfvL[2][2], bfvH[2][2];

    // ---- phase A: read afL(8) + bfvL(4) ; MFMA Q0
#pragma unroll
    for (int m = 0; m < 4; ++m)
#pragma unroll
      for (int kk = 0; kk < 2; ++kk)
        afL[m][kk] = *(const bf16x8*)(Ab + (wm * 128 + m * 16 + frow) * 128 +
                                      ((kk * 64 + fkb) ^ fswz));
#pragma unroll
    for (int n = 0; n < 2; ++n)
#pragma unroll
      for (int kk = 0; kk < 2; ++kk)
        bfvL[n][kk] = *(const bf16x8*)(Bb + (wn * 64 + n * 16 + frow) * 128 +
                                       ((kk * 64 + fkb) ^ fswz));
    __builtin_amdgcn_s_barrier();
    asm volatile("s_waitcnt lgkmcnt(0)");
    __builtin_amdgcn_sched_barrier(0);
    __builtin_amdgcn_s_setprio(1);
#pragma unroll
    for (int m = 0; m < 4; ++m)
#pragma unroll
      for (int n = 0; n < 2; ++n)
#pragma unroll
        for (int kk = 0; kk < 2; ++kk)
          acc[m][n] = __builtin_amdgcn_mfma_f32_16x16x32_bf16(
              afL[m][kk], bfvL[n][kk], acc[m][n], 0, 0, 0);
    __builtin_amdgcn_s_setprio(0);
    __builtin_amdgcn_s_barrier();

    // ---- phase B: read bfvH(4) ; MFMA Q1
#pragma unroll
    for (int n = 0; n < 2; ++n)
#pragma unroll
      for (int kk = 0; kk < 2; ++kk)
        bfvH[n][kk] = *(const bf16x8*)(Bb + (wn * 64 + (n + 2) * 16 + frow) * 128 +
                                       ((kk * 64 + fkb) ^ fswz));
    __builtin_amdgcn_s_barrier();
    asm volatile("s_waitcnt lgkmcnt(0)");
    __builtin_amdgcn_sched_barrier(0);
    __builtin_amdgcn_s_setprio(1);
#pragma unroll
    for (int m = 0; m < 4; ++m)
#pragma unroll
      for (int n = 0; n < 2; ++n)
#pragma unroll
        for (int kk = 0; kk < 2; ++kk)
          acc[m][n + 2] = __builtin_amdgcn_mfma_f32_16x16x32_bf16(
              afL[m][kk], bfvH[n][kk], acc[m][n + 2], 0, 0, 0);
    __builtin_amdgcn_s_setprio(0);
    __builtin_amdgcn_s_barrier();
    // all B-region reads of tile t are now drained (end-of-B barrier)

    // ---- phase C: read afH(8) ; stage B(t+2) ; MFMA Q2
#pragma unroll
    for (int m = 0; m < 4; ++m)
#pragma unroll
      for (int kk = 0; kk < 2; ++kk)
        afH[m][kk] = *(const bf16x8*)(Ab + (wm * 128 + (m + 4) * 16 + frow) * 128 +
                                      ((kk * 64 + fkb) ^ fswz));
    if (t + 2 < NT) { stageB(t + 2, 0); stageB(t + 2, 1); }
    __builtin_amdgcn_s_barrier();
    asm volatile("s_waitcnt lgkmcnt(0)");
    __builtin_amdgcn_sched_barrier(0);
    __builtin_amdgcn_s_setprio(1);
#pragma unroll
    for (int m = 0; m < 4; ++m)
#pragma unroll
      for (int n = 0; n < 2; ++n)
#pragma unroll
        for (int kk = 0; kk < 2; ++kk)
          acc[m + 4][n] = __builtin_amdgcn_mfma_f32_16x16x32_bf16(
              afH[m][kk], bfvL[n][kk], acc[m + 4][n], 0, 0, 0);
    __builtin_amdgcn_s_setprio(0);
    __builtin_amdgcn_s_barrier();
    // all A-region reads of tile t are now drained (end-of-C barrier)

    // ---- phase D: stage A(t+2) ; counted vmcnt ; MFMA Q3
    if (t + 2 < NT) {
      stageA(t + 2, 0); stageA(t + 2, 1);
      asm volatile("s_waitcnt vmcnt(8)");   // tile t+1 fully landed
    } else {
      asm volatile("s_waitcnt vmcnt(0)");   // tail drain
    }
    __builtin_amdgcn_s_barrier();
    __builtin_amdgcn_s_setprio(1);
#pragma unroll
    for (int m = 0; m < 4; ++m)
#pragma unroll
      for (int n = 0; n < 2; ++n)
#pragma unroll
        for (int kk = 0; kk < 2; ++kk)
          acc[m + 4][n + 2] = __builtin_amdgcn_mfma_f32_16x16x32_bf16(
              afH[m][kk], bfvH[n][kk], acc[m + 4][n + 2], 0, 0, 0);
    __builtin_amdgcn_s_setprio(0);
    __builtin_amdgcn_s_barrier();
  }

  // epilogue: C/D layout col=lane&15, row=(lane>>4)*4+reg [m89]
  const long rb0 = brow + wm * 128 + (lane >> 4) * 4;
  const long cb0 = bcol + wn * 64 + (lane & 15);
#pragma unroll
  for (int m = 0; m < 8; ++m) {
#pragma unroll
    for (int n = 0; n < 4; ++n) {
      const long col = cb0 + n * 16;
      const float bv = bi ? bi[col] : 0.f;
#pragma unroll
      for (int j = 0; j < 4; ++j) {
        const long r = rb0 + m * 16 + j;
        float v = acc[m][n][j] + bv;
        if (relu) v = fmaxf(v, 0.f);
        if (out_f32) {
          float* cp = (float*)Cq + r * (long)ldc + col;
          if (resadd) v += *cp;
          *cp = v;
        } else {
          ((unsigned short*)Cq)[r * (long)ldc + col] = f2bf(v);
        }
      }
    }
  }
}

// ---------------------------------------------------------------------------
// Legacy 128x128 GEMM — fallback path only.
// ---------------------------------------------------------------------------
__global__ __launch_bounds__(256) void gemm_bt_kernel(
    const unsigned short* __restrict__ A, int lda,
    const unsigned short* __restrict__ B, int K,
    void* __restrict__ Cp, int ldc,
    const float* __restrict__ bias,
    const void* __restrict__ res, int res_mode, int ldres,
    int relu, int out_f32) {
  __shared__ __align__(16) unsigned short As[128 * 32];
  __shared__ __align__(16) unsigned short Bs[128 * 32];

  const int t = threadIdx.x;
  const int lane = t & 63;
  const int w = t >> 6;
  const int wr = (w >> 1) * 64;
  const int wc = (w & 1) * 64;
  const long brow = (long)blockIdx.y * 128;
  const long bcol = (long)blockIdx.x * 128;

  const int srow = lane >> 2;
  const int scol = (lane & 3) * 8;
  const unsigned short* Ab = A + (brow + w * 32 + srow) * (long)lda + scol;
  const unsigned short* Bb = B + (bcol + w * 32 + srow) * (long)K + scol;
  unsigned short* Asb = &As[(w * 32) * 32];
  unsigned short* Bsb = &Bs[(w * 32) * 32];

  f32x4 acc[4][4];
  const f32x4 fzero = {0.f, 0.f, 0.f, 0.f};
#pragma unroll
  for (int m = 0; m < 4; ++m)
#pragma unroll
    for (int n = 0; n < 4; ++n) acc[m][n] = fzero;

  const int fr = lane & 15;
  const int fk = (lane >> 4) * 8;

  for (int kt = 0; kt < K; kt += 32) {
    gload_lds16(Ab + kt, Asb);
    gload_lds16(Ab + 16 * (long)lda + kt, Asb + 16 * 32);
    gload_lds16(Bb + kt, Bsb);
    gload_lds16(Bb + 16 * (long)K + kt, Bsb + 16 * 32);
    __syncthreads();

    bf16x8 af[4], bfv[4];
#pragma unroll
    for (int m = 0; m < 4; ++m)
      af[m] = *(const bf16x8*)&As[(wr + m * 16 + fr) * 32 + fk];
#pragma unroll
    for (int n = 0; n < 4; ++n)
      bfv[n] = *(const bf16x8*)&Bs[(wc + n * 16 + fr) * 32 + fk];
#pragma unroll
    for (int m = 0; m < 4; ++m)
#pragma unroll
      for (int n = 0; n < 4; ++n)
        acc[m][n] = __builtin_amdgcn_mfma_f32_16x16x32_bf16(af[m], bfv[n],
                                                            acc[m][n], 0, 0, 0);
    __syncthreads();
  }

  const long rbase = brow + wr + (lane >> 4) * 4;
#pragma unroll
  for (int m = 0; m < 4; ++m) {
#pragma unroll
    for (int n = 0; n < 4; ++n) {
      const long col = bcol + wc + n * 16 + fr;
      const float bv = bias ? bias[col] : 0.f;
#pragma unroll
      for (int j = 0; j < 4; ++j) {
        const long r = rbase + m * 16 + j;
        float v = acc[m][n][j] + bv;
        if (relu) v = fmaxf(v, 0.f);
        if (res_mode == 1)
          v += ((const float*)res)[r * (long)ldres + col];
        else if (res_mode == 2)
          v += bf2f(((const unsigned short*)res)[r * (long)ldres + col]);
        if (out_f32)
          ((float*)Cp)[r * (long)ldc + col] = v;
        else
          ((unsigned short*)Cp)[r * (long)ldc + col] = f2bf(v);
      }
    }
  }
}

// ---------------------------------------------------------------------------
template <int L>
__global__ __launch_bounds__(256) void ln_kernel(
    const void* __restrict__ inp, int in_bf16, int ldin,
    const float* __restrict__ g, const float* __restrict__ b,
    unsigned short* __restrict__ outp, int ldout) {
  constexpr int VEC = L / 256;
  const long row = blockIdx.x;
  const int t = threadIdx.x;
  float v[VEC];
  if (in_bf16) {
    const unsigned short* p = (const unsigned short*)inp + row * (long)ldin + t * VEC;
#pragma unroll
    for (int i = 0; i < VEC; i += 4) {
      ushort4 u = *(const ushort4*)(p + i);
      v[i] = bf2f(u.x); v[i + 1] = bf2f(u.y); v[i + 2] = bf2f(u.z); v[i + 3] = bf2f(u.w);
    }
  } else {
    const float* p = (const float*)inp + row * (long)ldin + t * VEC;
#pragma unroll
    for (int i = 0; i < VEC; i += 4) {
      float4 f = *(const float4*)(p + i);
      v[i] = f.x; v[i + 1] = f.y; v[i + 2] = f.z; v[i + 3] = f.w;
    }
  }
  float s = 0.f, sq = 0.f;
#pragma unroll
  for (int i = 0; i < VEC; ++i) { s += v[i]; sq += v[i] * v[i]; }
#pragma unroll
  for (int off = 32; off; off >>= 1) {
    s += __shfl_xor(s, off, 64);
    sq += __shfl_xor(sq, off, 64);
  }
  __shared__ float red[8];
  if ((t & 63) == 0) { red[t >> 6] = s; red[4 + (t >> 6)] = sq; }
  __syncthreads();
  s = red[0] + red[1] + red[2] + red[3];
  sq = red[4] + red[5] + red[6] + red[7];
  const float mean = s * (1.f / L);
  const float var = sq * (1.f / L) - mean * mean;
  const float rstd = rsqrtf(var + 1e-6f);
  unsigned short* op = outp + row * (long)ldout + t * VEC;
  const float* gp = g + t * VEC;
  const float* bp = b + t * VEC;
#pragma unroll
  for (int i = 0; i < VEC; i += 4) {
    float4 gg = *(const float4*)(gp + i);
    float4 bb = *(const float4*)(bp + i);
    *(ushort4*)(op + i) = make_ushort4(
        f2bf((v[i + 0] - mean) * rstd * gg.x + bb.x),
        f2bf((v[i + 1] - mean) * rstd * gg.y + bb.y),
        f2bf((v[i + 2] - mean) * rstd * gg.z + bb.z),
        f2bf((v[i + 3] - mean) * rstd * gg.w + bb.w));
  }
}

// ---------------------------------------------------------------------------
__global__ __launch_bounds__(512) void attn_glue_kernel(
    const unsigned short* __restrict__ Q, const unsigned short* __restrict__ Kq,
    const unsigned short* __restrict__ V, int ld, const void* __restrict__ Xres,
    int res_bf16, void* __restrict__ Xout, int out_bf16,
    unsigned short* __restrict__ Xout_bf) {
  const long row = blockIdx.x;
  const int h = threadIdx.x >> 6;
  const int lane = threadIdx.x & 63;
  const long qbase = row * (long)ld + h * 256;
  const long xbase = row * 2048 + h * 256;
  const int d = lane * 2;

  ushort2 q0 = *(const ushort2*)&Q[qbase + d];
  ushort2 q1 = *(const ushort2*)&Q[qbase + 128 + d];
  ushort2 k0 = *(const ushort2*)&Kq[qbase + d];
  ushort2 k1 = *(const ushort2*)&Kq[qbase + 128 + d];
  ushort2 v0 = *(const ushort2*)&V[qbase + d];
  ushort2 v1 = *(const ushort2*)&V[qbase + 128 + d];

  const float q0x = bf2f(q0.x), q0y = bf2f(q0.y);
  const float q1x = bf2f(q1.x), q1y = bf2f(q1.y);
  const float k0x = bf2f(k0.x), k0y = bf2f(k0.y);
  const float k1x = bf2f(k1.x), k1y = bf2f(k1.y);

  float s00 = q0x * k0x + q0y * k0y;
  float s01 = q0x * k1x + q0y * k1y;
  float s10 = q1x * k0x + q1y * k0y;
  float s11 = q1x * k1x + q1y * k1y;
#pragma unroll
  for (int off = 32; off; off >>= 1) {
    s00 += __shfl_xor(s00, off, 64);
    s01 += __shfl_xor(s01, off, 64);
    s10 += __shfl_xor(s10, off, 64);
    s11 += __shfl_xor(s11, off, 64);
  }
  const float SC = 0.088388347648318447f;  // 1/sqrt(128)
  s00 *= SC; s01 *= SC; s10 *= SC; s11 *= SC;
  const float m0 = fmaxf(s00, s01), m1 = fmaxf(s10, s11);
  const float e00 = __expf(s00 - m0), e01 = __expf(s01 - m0);
  const float e10 = __expf(s10 - m1), e11 = __expf(s11 - m1);
  const float i0 = 1.f / (e00 + e01), i1 = 1.f / (e10 + e11);
  const float a00 = e00 * i0, a01 = e01 * i0;
  const float a10 = e10 * i1, a11 = e11 * i1;

  const float v0x = bf2f(v0.x), v0y = bf2f(v0.y);
  const float v1x = bf2f(v1.x), v1y = bf2f(v1.y);
  float o0x = a00 * v0x + a01 * v1x, o0y = a00 * v0y + a01 * v1y;
  float o1x = a10 * v0x + a11 * v1x, o1y = a10 * v0y + a11 * v1y;

  if (res_bf16) {
    const unsigned short* xr = (const unsigned short*)Xres + xbase;
    ushort2 ra = *(const ushort2*)&xr[d];
    ushort2 rb = *(const ushort2*)&xr[128 + d];
    o0x += bf2f(ra.x); o0y += bf2f(ra.y); o1x += bf2f(rb.x); o1y += bf2f(rb.y);
  } else {
    const float* xr = (const float*)Xres + xbase;
    float2 ra = *(const float2*)&xr[d];
    float2 rb = *(const float2*)&xr[128 + d];
    o0x += ra.x; o0y += ra.y; o1x += rb.x; o1y += rb.y;
  }
  if (out_bf16) {
    unsigned short* xo = (unsigned short*)Xout + xbase;
    *(ushort2*)&xo[d] = make_ushort2(f2bf(o0x), f2bf(o0y));
    *(ushort2*)&xo[128 + d] = make_ushort2(f2bf(o1x), f2bf(o1y));
  } else {
    float* xo = (float*)Xout + xbase;
    *(float2*)&xo[d] = make_float2(o0x, o0y);
    *(float2*)&xo[128 + d] = make_float2(o1x, o1y);
  }
  if (Xout_bf) {
    unsigned short* xb = Xout_bf + xbase;
    *(ushort2*)&xb[d] = make_ushort2(f2bf(o0x), f2bf(o0y));
    *(ushort2*)&xb[128 + d] = make_ushort2(f2bf(o1x), f2bf(o1y));
  }
}

__global__ __launch_bounds__(256) void final_matvec_kernel(
    const unsigned short* __restrict__ Hm, const float* __restrict__ wv,
    const float* __restrict__ b2, float* __restrict__ outp) {
  const long row = blockIdx.x;
  const int t = threadIdx.x;
  ushort4 hv = *(const ushort4*)&Hm[row * 1024 + t * 4];
  float4 wq = *(const float4*)&wv[t * 4];
  float s = bf2f(hv.x) * wq.x + bf2f(hv.y) * wq.y +
            bf2f(hv.z) * wq.z + bf2f(hv.w) * wq.w;
#pragma unroll
  for (int off = 32; off; off >>= 1) s += __shfl_xor(s, off, 64);
  __shared__ float red[4];
  if ((t & 63) == 0) red[t >> 6] = s;
  __syncthreads();
  if (t == 0) outp[row] = red[0] + red[1] + red[2] + red[3] + b2[0];
}

// ---------------------------------------------------------------------------
extern "C" void kernel_launch(void* const* d_in, const int* in_sizes, int n_in,
                              void* d_out, int out_size, void* d_ws,
                              size_t ws_size, hipStream_t stream) {
  const float* x_in = (const float*)d_in[0];
  const float* aln_g = (const float*)d_in[1];
  const float* aln_b = (const float*)d_in[2];
  const float* Wq_f = (const float*)d_in[3];
  const float* Wk_f = (const float*)d_in[4];
  const float* Wv_f = (const float*)d_in[5];
  const float* lnd_g = (const float*)d_in[6];
  const float* lnd_b = (const float*)d_in[7];
  const float* lnt_g = (const float*)d_in[8];
  const float* lnt_b = (const float*)d_in[9];
  const float* Wd1_f = (const float*)d_in[10];
  const float* bd1 = (const float*)d_in[11];
  const float* Wd2_f = (const float*)d_in[12];
  const float* bd2 = (const float*)d_in[13];
  const float* Wt1_f = (const float*)d_in[14];
  const float* bt1 = (const float*)d_in[15];
  const float* Wt2_f = (const float*)d_in[16];
  const float* bt2 = (const float*)d_in[17];
  const float* Wo1_f = (const float*)d_in[18];
  const float* bo1 = (const float*)d_in[19];
  const float* Wo2_f = (const float*)d_in[20];
  const float* bo2 = (const float*)d_in[21];

  const size_t R = 8192, D = 2048, HD = 1024;
  const size_t DD = D * D;
  const size_t WALL = (3 * 3 * DD + 4 * 2 * D * HD + HD * D) * 2;  // 108 MiB
  const size_t SLOT = 3 * DD * 2;                                  // 24 MiB
  const size_t ACT = R * D * 4 + R * D * 2 + R * 6144 * 2;         // 192 MiB

  auto cvt = [&](const float* src, unsigned short* dst, long n) {
    cvt_kernel<<<dim3((unsigned)(n / 1024)), dim3(256), 0, stream>>>(src, dst, n);
  };

  if (ws_size >= ACT + SLOT) {
    // ===================== fast path (8-phase GEMMs) =====================
    const bool planAll = ws_size >= ACT + WALL;
    hipFuncSetAttribute(reinterpret_cast<const void*>(gemm8_kernel),
                        hipFuncAttributeMaxDynamicSharedMemorySize, 131072);

    char* p = (char*)d_ws;
    float* Xf = (float*)p; p += R * D * 4;
    unsigned short* XN = (unsigned short*)p; p += R * D * 2;
    unsigned short* QKVb = (unsigned short*)p; p += R * 6144 * 2;
    unsigned short* Warea = (unsigned short*)p;

    unsigned short* H1d = QKVb;
    unsigned short* H1t = QKVb + R * 2048;
    unsigned short* Hfin = QKVb + R * 4096;
    unsigned short* DN = XN;
    unsigned short* TN = XN + R * HD;

    unsigned short* Wqkv_b = Warea;
    unsigned short* Wd1_b = Wqkv_b + 9 * DD;
    unsigned short* Wt1_b = Wd1_b + 2 * D * HD;
    unsigned short* Wd2_b = Wt1_b + 2 * D * HD;
    unsigned short* Wt2_b = Wd2_b + 2 * D * HD;
    unsigned short* Wo1_b = Wt2_b + 2 * D * HD;
    if (planAll) {
      for (int n = 0; n < 3; ++n) {
        cvt(Wq_f + n * DD, Wqkv_b + n * 3 * DD + 0 * DD, DD);
        cvt(Wk_f + n * DD, Wqkv_b + n * 3 * DD + 1 * DD, DD);
        cvt(Wv_f + n * DD, Wqkv_b + n * 3 * DD + 2 * DD, DD);
      }
      cvt(Wd1_f, Wd1_b, 2 * D * HD);
      cvt(Wt1_f, Wt1_b, 2 * D * HD);
      cvt(Wd2_f, Wd2_b, 2 * D * HD);
      cvt(Wt2_f, Wt2_b, 2 * D * HD);
      cvt(Wo1_f, Wo1_b, HD * D);
    }

    auto gemm8 = [&](const unsigned short* A, int lda, const unsigned short* B,
                     int N, int K, void* C, int ldc, const float* bias,
                     int relu, int of32, int resadd, const unsigned short* A2,
                     const unsigned short* B2, void* C2, const float* bias2) {
      const int dual = (A2 != nullptr);
      dim3 grid((dual ? 2 : 1) * (N / 256), 32);
      gemm8_kernel<<<grid, dim3(512), 131072, stream>>>(
          A, lda, B, K, C, ldc, bias, relu, of32, resadd, A2, B2, C2, bias2,
          dual);
    };

    for (int n = 0; n < 3; ++n) {
      ln_kernel<2048><<<8192, 256, 0, stream>>>(
          (n == 0) ? (const void*)x_in : (const void*)Xf, 0, 2048,
          aln_g + n * D, aln_b + n * D, XN, 2048);
      const unsigned short* Wqkv;
      if (planAll) {
        Wqkv = Wqkv_b + (size_t)n * 3 * DD;
      } else {
        cvt(Wq_f + n * DD, Warea + 0 * DD, DD);
        cvt(Wk_f + n * DD, Warea + 1 * DD, DD);
        cvt(Wv_f + n * DD, Warea + 2 * DD, DD);
        Wqkv = Warea;
      }
      gemm8(XN, 2048, Wqkv, 6144, 2048, QKVb, 6144, nullptr, 0, 0, 0,
            nullptr, nullptr, nullptr, nullptr);
      attn_glue_kernel<<<8192, 512, 0, stream>>>(
          QKVb, QKVb + 2048, QKVb + 4096, 6144,
          (n == 0) ? (const void*)x_in : (const void*)Xf, 0, Xf, 0,
          (n == 2) ? XN : nullptr);

      if (n < 2) {
        const size_t fo = (size_t)n * D * HD;
        ln_kernel<1024><<<8192, 256, 0, stream>>>(Xf, 0, 2048, lnd_g + n * HD,
                                                  lnd_b + n * HD, DN, 1024);
        ln_kernel<1024><<<8192, 256, 0, stream>>>(Xf + HD, 0, 2048,
                                                  lnt_g + n * HD,
                                                  lnt_b + n * HD, TN, 1024);
        const unsigned short *w1d, *w1t, *w2d, *w2t;
        if (planAll) {
          w1d = Wd1_b + fo; w1t = Wt1_b + fo; w2d = Wd2_b + fo; w2t = Wt2_b + fo;
        } else {
          cvt(Wd1_f + fo, Warea + 0 * D * HD, D * HD);
          cvt(Wt1_f + fo, Warea + 1 * D * HD, D * HD);
          cvt(Wd2_f + fo, Warea + 2 * D * HD, D * HD);
          cvt(Wt2_f + fo, Warea + 3 * D * HD, D * HD);
          w1d = Warea; w1t = Warea + D * HD; w2d = Warea + 2 * D * HD;
          w2t = Warea + 3 * D * HD;
        }
        // dual up-proj: DN -> H1d, TN -> H1t
        gemm8(DN, 1024, w1d, 2048, 1024, H1d, 2048, bd1 + n * D, 1, 0, 0,
              TN, w1t, H1t, bt1 + n * D);
        // dual down-proj: d-half -> X[:, :1024], t-half -> X[:, 1024:]
        gemm8(H1d, 2048, w2d, 1024, 2048, Xf, 2048, bd2 + n * HD, 0, 1, 1,
              H1t, w2t, Xf + HD, bt2 + n * HD);
      }
    }

    // final head: Hfin = relu(Xbf @ Wo1^T + bo1); out = Hfin @ Wo2^T + bo2
    const unsigned short* Wo1p;
    if (planAll) {
      Wo1p = Wo1_b;
    } else {
      cvt(Wo1_f, Warea, HD * D);
      Wo1p = Warea;
    }
    gemm8(XN, 2048, Wo1p, 1024, 2048, Hfin, 1024, bo1, 1, 0, 0,
          nullptr, nullptr, nullptr, nullptr);
    final_matvec_kernel<<<8192, 256, 0, stream>>>(Hfin, Wo2_f, bo2,
                                                  (float*)d_out);
    return;
  }

  // ======================= legacy fallback path =======================
  const size_t PLB = R * D * 2;
  const size_t XFZ = R * D * 4;
  const size_t SLOT1 = DD * 2;
  const bool planAll = ws_size >= XFZ + 4 * PLB + WALL;
  const bool xIsF32 = planAll || ws_size >= XFZ + 4 * PLB + SLOT1;

  char* p = (char*)d_ws;
  float* Xf = nullptr;
  unsigned short* Xb = nullptr;
  if (xIsF32) { Xf = (float*)p; p += XFZ; } else { Xb = (unsigned short*)p; p += PLB; }
  unsigned short* XN = (unsigned short*)p; p += PLB;
  unsigned short* Qb = (unsigned short*)p; p += PLB;
  unsigned short* Kb = (unsigned short*)p; p += PLB;
  unsigned short* Vb = (unsigned short*)p; p += PLB;
  unsigned short* Warea = (unsigned short*)p;

  void* X = xIsF32 ? (void*)Xf : (void*)Xb;
  const int xres_mode = xIsF32 ? 1 : 2;
  unsigned short* H1 = Qb;
  unsigned short* DN = XN;
  unsigned short* TN = XN + R * HD;
  unsigned short* Hfin = Vb;

  unsigned short* Wq_b = Warea;
  unsigned short* Wk_b = Wq_b + 3 * DD;
  unsigned short* Wv_b = Wk_b + 3 * DD;
  unsigned short* Wd1_b = Wv_b + 3 * DD;
  unsigned short* Wd2_b = Wd1_b + 2 * D * HD;
  unsigned short* Wt1_b = Wd2_b + 2 * D * HD;
  unsigned short* Wt2_b = Wt1_b + 2 * D * HD;
  unsigned short* Wo1_b = Wt2_b + 2 * D * HD;
  if (planAll) {
    cvt(Wq_f, Wq_b, 3 * DD);
    cvt(Wk_f, Wk_b, 3 * DD);
    cvt(Wv_f, Wv_b, 3 * DD);
    cvt(Wd1_f, Wd1_b, 2 * D * HD);
    cvt(Wd2_f, Wd2_b, 2 * D * HD);
    cvt(Wt1_f, Wt1_b, 2 * D * HD);
    cvt(Wt2_f, Wt2_b, 2 * D * HD);
    cvt(Wo1_f, Wo1_b, HD * D);
  }
  auto wbf = [&](const float* src_base, unsigned short* pre_base, size_t off,
                 size_t cnt) -> const unsigned short* {
    if (planAll) return pre_base + off;
    cvt(src_base + off, Warea, (long)cnt);
    return Warea;
  };
  auto gemm = [&](const unsigned short* A, int lda, const unsigned short* B,
                  int N, int K, void* C, int ldc, const float* bias,
                  const void* res, int res_mode, int ldres, int relu, int of32) {
    dim3 grid(N / 128, 8192 / 128);
    gemm_bt_kernel<<<grid, dim3(256), 0, stream>>>(
        A, lda, B, K, C, ldc, bias, res, res_mode, ldres, relu, of32);
  };

  for (int n = 0; n < 3; ++n) {
    const void* lin = (n == 0) ? (const void*)x_in : (const void*)X;
    const int lin_bf16 = (n == 0) ? 0 : (xIsF32 ? 0 : 1);
    ln_kernel<2048><<<8192, 256, 0, stream>>>(lin, lin_bf16, 2048,
                                              aln_g + n * D, aln_b + n * D, XN, 2048);
    const size_t wo = (size_t)n * DD;
    gemm(XN, 2048, wbf(Wq_f, Wq_b, wo, DD), 2048, 2048, Qb, 2048,
         nullptr, nullptr, 0, 0, 0, 0);
    gemm(XN, 2048, wbf(Wk_f, Wk_b, wo, DD), 2048, 2048, Kb, 2048,
         nullptr, nullptr, 0, 0, 0, 0);
    gemm(XN, 2048, wbf(Wv_f, Wv_b, wo, DD), 2048, 2048, Vb, 2048,
         nullptr, nullptr, 0, 0, 0, 0);
    attn_glue_kernel<<<8192, 512, 0, stream>>>(
        Qb, Kb, Vb, 2048, (n == 0) ? (const void*)x_in : (const void*)X,
        (n == 0) ? 0 : (xIsF32 ? 0 : 1), X, xIsF32 ? 0 : 1,
        (n == 2 && xIsF32) ? XN : nullptr);

    if (n < 2) {
      const size_t fo = (size_t)n * D * HD;
      ln_kernel<1024><<<8192, 256, 0, stream>>>(X, !xIsF32, 2048,
                                                lnd_g + n * HD, lnd_b + n * HD, DN, 1024);
      const void* Xt = xIsF32 ? (const void*)(Xf + HD) : (const void*)(Xb + HD);
      ln_kernel<1024><<<8192, 256, 0, stream>>>(Xt, !xIsF32, 2048,
                                                lnt_g + n * HD, lnt_b + n * HD, TN, 1024);
      void* Xd2 = X;
      void* Xt2 = xIsF32 ? (void*)(Xf + HD) : (void*)(Xb + HD);
      gemm(DN, 1024, wbf(Wd1_f, Wd1_b, fo, D * HD), 2048, 1024, H1, 2048,
           bd1 + n * D, nullptr, 0, 0, 1, 0);
      gemm(H1, 2048, wbf(Wd2_f, Wd2_b, fo, D * HD), 1024, 2048, Xd2, 2048,
           bd2 + n * HD, Xd2, xres_mode, 2048, 0, xIsF32 ? 1 : 0);
      gemm(TN, 1024, wbf(Wt1_f, Wt1_b, fo, D * HD), 2048, 1024, H1, 2048,
           bt1 + n * D, nullptr, 0, 0, 1, 0);
      gemm(H1, 2048, wbf(Wt2_f, Wt2_b, fo, D * HD), 1024, 2048, Xt2, 2048,
           bt2 + n * HD, Xt2, xres_mode, 2048, 0, xIsF32 ? 1 : 0);
    }
  }

  const unsigned short* Afin = xIsF32 ? XN : Xb;
  gemm(Afin, 2048, wbf(Wo1_f, Wo1_b, 0, HD * D), 1024, 2048, Hfin, 1024,
       bo1, nullptr, 0, 0, 1, 0);
  final_matvec_kernel<<<8192, 256, 0, stream>>>(Hfin, Wo2_f, bo2, (float*)d_out);
}